// Round 1
// baseline (3573.219 us; speedup 1.0000x reference)
//
#include <hip/hip_runtime.h>
#include <math.h>

#define NN 40000
#define NE 640000
#define KIN 776
#define HH 128
#define NCLS 5

#define TM 64
#define TN 64
#define TK 16

enum { A_PLAIN = 0, A_EDGE = 1, A_BN = 2 };

// Tiled f32 GEMM: C[M,HH-wide tiles] = A[M,K] @ B[K,128] + bias, with fused
// A-side modes (plain / edge-encoder-on-the-fly / BN+ReLU) and epilogue modes
// (gather Dh[src]+Eh[dst], sigmoid+atomic segment-sum, relu, store).
template<int AMODE, bool GATHER, bool SIGMA, bool RELUOUT, bool STOREC>
__global__ __launch_bounds__(256)
void gemm_k(const float* __restrict__ A, int K,
            const float* __restrict__ B, const float* __restrict__ bias,
            float* __restrict__ C,
            const float* __restrict__ ef, const float* __restrict__ eW,
            const float* __restrict__ eB, const float* __restrict__ bnp,
            const float* __restrict__ Dh, const float* __restrict__ Eh,
            const int* __restrict__ src, const int* __restrict__ dst,
            const float* __restrict__ Bh, float* __restrict__ num,
            float* __restrict__ den)
{
    __shared__ float As[TK][TM + 4];   // transposed A tile, padded
    __shared__ float Bs[TK][TN];
    const int tid = threadIdx.x;
    const int m0 = blockIdx.x * TM;
    const int n0 = blockIdx.y * TN;
    const int tx = tid & 15, ty = tid >> 4;
    const int arow = tid >> 2, akc = (tid & 3) * 4;
    const int brow = tid >> 4, bcol = (tid & 15) * 4;

    float acc[4][4] = {};

    for (int kt = 0; kt < K; kt += TK) {
        // ---- A tile ----
        float4 av;
        const int gr = m0 + arow;
        if (AMODE == A_EDGE) {
            const float f0 = ef[(size_t)gr * 2 + 0];
            const float f1 = ef[(size_t)gr * 2 + 1];
            const int k = kt + akc;
            const float4 w0 = *(const float4*)(eW + k);
            const float4 w1 = *(const float4*)(eW + HH + k);
            const float4 b4 = *(const float4*)(eB + k);
            av.x = fmaf(f0, w0.x, fmaf(f1, w1.x, b4.x));
            av.y = fmaf(f0, w0.y, fmaf(f1, w1.y, b4.y));
            av.z = fmaf(f0, w0.z, fmaf(f1, w1.z, b4.z));
            av.w = fmaf(f0, w0.w, fmaf(f1, w1.w, b4.w));
        } else {
            const int k = kt + akc;
            if (k + 3 < K) {
                av = *(const float4*)(A + (size_t)gr * K + k);
            } else {
                av.x = (k + 0 < K) ? A[(size_t)gr * K + k + 0] : 0.f;
                av.y = (k + 1 < K) ? A[(size_t)gr * K + k + 1] : 0.f;
                av.z = (k + 2 < K) ? A[(size_t)gr * K + k + 2] : 0.f;
                av.w = (k + 3 < K) ? A[(size_t)gr * K + k + 3] : 0.f;
            }
            if (AMODE == A_BN) {
                const float4 sc = *(const float4*)(bnp + k);
                const float4 sh = *(const float4*)(bnp + HH + k);
                av.x = fmaxf(fmaf(av.x, sc.x, sh.x), 0.f);
                av.y = fmaxf(fmaf(av.y, sc.y, sh.y), 0.f);
                av.z = fmaxf(fmaf(av.z, sc.z, sh.z), 0.f);
                av.w = fmaxf(fmaf(av.w, sc.w, sh.w), 0.f);
            }
        }
        As[akc + 0][arow] = av.x;
        As[akc + 1][arow] = av.y;
        As[akc + 2][arow] = av.z;
        As[akc + 3][arow] = av.w;

        // ---- B tile ----
        {
            const int k = kt + brow;
            float4 bv = make_float4(0.f, 0.f, 0.f, 0.f);
            if (k < K) bv = *(const float4*)(B + (size_t)k * HH + n0 + bcol);
            *(float4*)&Bs[brow][bcol] = bv;
        }
        __syncthreads();

        #pragma unroll
        for (int kk = 0; kk < TK; ++kk) {
            const float4 a4 = *(const float4*)&As[kk][ty * 4];
            const float4 b4 = *(const float4*)&Bs[kk][tx * 4];
            const float avr[4] = {a4.x, a4.y, a4.z, a4.w};
            const float bvr[4] = {b4.x, b4.y, b4.z, b4.w};
            #pragma unroll
            for (int i = 0; i < 4; ++i)
                #pragma unroll
                for (int j = 0; j < 4; ++j)
                    acc[i][j] = fmaf(avr[i], bvr[j], acc[i][j]);
        }
        __syncthreads();
    }

    const int colbase = n0 + tx * 4;
    const float4 bb = *(const float4*)(bias + colbase);
    const float biasv[4] = {bb.x, bb.y, bb.z, bb.w};
    #pragma unroll
    for (int i = 0; i < 4; ++i) {
        const int gr = m0 + ty * 4 + i;
        float v[4];
        #pragma unroll
        for (int j = 0; j < 4; ++j) v[j] = acc[i][j] + biasv[j];
        int sI = 0, dI = 0;
        if (GATHER) {
            sI = src[gr]; dI = dst[gr];
            const float4 dh = *(const float4*)(Dh + (size_t)sI * HH + colbase);
            const float4 eh = *(const float4*)(Eh + (size_t)dI * HH + colbase);
            v[0] += dh.x + eh.x; v[1] += dh.y + eh.y;
            v[2] += dh.z + eh.z; v[3] += dh.w + eh.w;
        }
        if (RELUOUT) {
            #pragma unroll
            for (int j = 0; j < 4; ++j) v[j] = fmaxf(v[j], 0.f);
        }
        if (STOREC) {
            const float4 o = make_float4(v[0], v[1], v[2], v[3]);
            *(float4*)(C + (size_t)gr * HH + colbase) = o;
        }
        if (SIGMA) {
            const float4 bh = *(const float4*)(Bh + (size_t)sI * HH + colbase);
            const float bhv[4] = {bh.x, bh.y, bh.z, bh.w};
            #pragma unroll
            for (int j = 0; j < 4; ++j) {
                const float sg = 1.f / (1.f + __expf(-v[j]));
                atomicAdd(den + (size_t)dI * HH + colbase + j, sg);
                atomicAdd(num + (size_t)dI * HH + colbase + j, sg * bhv[j]);
            }
        }
    }
}

// Layer-1 edge post-pass: sigmoid + segment-sum atomics + BN column stats.
__global__ __launch_bounds__(256)
void edge_post(const float* __restrict__ enew, const int* __restrict__ src,
               const int* __restrict__ dst, const float* __restrict__ Bh,
               float* __restrict__ num, float* __restrict__ den,
               float* __restrict__ esum, float* __restrict__ esq)
{
    const int tid = threadIdx.x;
    const int c = tid & 127, sub = tid >> 7;
    const int e0 = blockIdx.x * 512;
    float sa = 0.f, qa = 0.f;
    for (int i = sub; i < 512; i += 2) {
        const int e = e0 + i;
        const float x = enew[(size_t)e * HH + c];
        const float sg = 1.f / (1.f + __expf(-x));
        const int d = dst[e], s = src[e];
        atomicAdd(den + (size_t)d * HH + c, sg);
        atomicAdd(num + (size_t)d * HH + c, sg * Bh[(size_t)s * HH + c]);
        sa += x; qa += x * x;
    }
    __shared__ float red[256];
    red[tid] = sa; __syncthreads();
    if (tid < 128) atomicAdd(esum + c, red[tid] + red[tid + 128]);
    __syncthreads();
    red[tid] = qa; __syncthreads();
    if (tid < 128) atomicAdd(esq + c, red[tid] + red[tid + 128]);
}

// h_new = Ah + num/(den+eps); store h_new; accumulate BN column stats.
__global__ __launch_bounds__(256)
void h_stats(const float* __restrict__ Ah, const float* __restrict__ num,
             const float* __restrict__ den, float* __restrict__ hnew,
             float* __restrict__ hsum, float* __restrict__ hsq)
{
    const int tid = threadIdx.x;
    const int c = tid & 127, sub = tid >> 7;
    const int r0 = blockIdx.x * 256;
    float sa = 0.f, qa = 0.f;
    for (int i = sub; i < 256; i += 2) {
        const int r = r0 + i;
        if (r >= NN) break;
        const size_t idx = (size_t)r * HH + c;
        const float x = Ah[idx] + num[idx] / (den[idx] + 1e-6f);
        hnew[idx] = x;
        sa += x; qa += x * x;
    }
    __shared__ float red[256];
    red[tid] = sa; __syncthreads();
    if (tid < 128) atomicAdd(hsum + c, red[tid] + red[tid + 128]);
    __syncthreads();
    red[tid] = qa; __syncthreads();
    if (tid < 128) atomicAdd(hsq + c, red[tid] + red[tid + 128]);
}

// BN params: scale = g*rsqrt(var+eps); shift = b - mean*scale.
__global__ void make_bnp(const float* __restrict__ sum, const float* __restrict__ sq,
                         const float* __restrict__ g, const float* __restrict__ b,
                         float cntInv, float* __restrict__ out)
{
    const int c = threadIdx.x;
    const float m = sum[c] * cntInv;
    const float var = sq[c] * cntInv - m * m;
    const float rs = rsqrtf(var + 1e-5f);
    const float sc = g[c] * rs;
    out[c] = sc;
    out[128 + c] = b[c] - m * sc;
}

// h = relu(hnew*scale + shift)
__global__ __launch_bounds__(256)
void h_apply(const float* __restrict__ hnew, const float* __restrict__ bnp,
             float* __restrict__ h)
{
    const int idx = blockIdx.x * 256 + threadIdx.x;   // float4 index
    const int c4 = (idx & 31) * 4;
    const float4 x = ((const float4*)hnew)[idx];
    const float4 sc = *(const float4*)(bnp + c4);
    const float4 sh = *(const float4*)(bnp + 128 + c4);
    float4 o;
    o.x = fmaxf(fmaf(x.x, sc.x, sh.x), 0.f);
    o.y = fmaxf(fmaf(x.y, sc.y, sh.y), 0.f);
    o.z = fmaxf(fmaf(x.z, sc.z, sh.z), 0.f);
    o.w = fmaxf(fmaf(x.w, sc.w, sh.w), 0.f);
    ((float4*)h)[idx] = o;
}

// logits = z @ mlp_w2 + mlp_b2  (z already relu'd)
__global__ __launch_bounds__(256)
void readout2(const float* __restrict__ z, const float* __restrict__ w2,
              const float* __restrict__ b2, float* __restrict__ out)
{
    const int idx = blockIdx.x * 256 + threadIdx.x;
    if (idx >= NN * NCLS) return;
    const int n = idx / NCLS, j = idx - n * NCLS;
    float acc = b2[j];
    const float* zr = z + (size_t)n * HH;
    for (int k = 0; k < HH; ++k) acc = fmaf(zr[k], w2[k * NCLS + j], acc);
    out[idx] = acc;
}

extern "C" void kernel_launch(void* const* d_in, const int* in_sizes, int n_in,
                              void* d_out, int out_size, void* d_ws, size_t ws_size,
                              hipStream_t stream)
{
    const float* node_feat = (const float*)d_in[0];
    const float* edge_feat = (const float*)d_in[1];
    const int*   src       = (const int*)d_in[2];
    const int*   dst       = (const int*)d_in[3];
    const float* enc_nw    = (const float*)d_in[4];
    const float* enc_nb    = (const float*)d_in[5];
    const float* enc_ew    = (const float*)d_in[6];
    const float* enc_eb    = (const float*)d_in[7];
    const float* lin_w     = (const float*)d_in[8];
    const float* lin_b     = (const float*)d_in[9];
    const float* bnh_g     = (const float*)d_in[10];
    const float* bnh_b     = (const float*)d_in[11];
    const float* bne_g     = (const float*)d_in[12];
    const float* bne_b     = (const float*)d_in[13];
    const float* mlp_w1    = (const float*)d_in[14];
    const float* mlp_b1    = (const float*)d_in[15];
    const float* mlp_w2    = (const float*)d_in[16];
    const float* mlp_b2    = (const float*)d_in[17];
    float* out = (float*)d_out;
    float* ws  = (float*)d_ws;

    const size_t NH = (size_t)NN * HH;   // 5,120,000 floats
    float* h     = ws;
    float* hnew  = ws + 1 * NH;
    float* Ah    = ws + 2 * NH;
    float* Bh    = ws + 3 * NH;
    float* Dh    = ws + 4 * NH;
    float* Eh    = ws + 5 * NH;
    float* num   = ws + 6 * NH;
    float* den   = ws + 7 * NH;
    float* stats = ws + 8 * NH;          // [hsum(128), hsq(128), esum(128), esq(128)]
    float* bnp   = stats + 1024;         // [ebnp(256), hbnp(256)]
    float* enew  = bnp + 512;            // E*H floats
    float* z     = hnew;                 // reuse for readout

    const dim3 blk(256);
    const dim3 gN(NN / TM, HH / TN);     // 625 x 2
    const dim3 gE(NE / TM, HH / TN);     // 10000 x 2

    // node encoder: h = node_feat @ enc_nw + enc_nb
    gemm_k<A_PLAIN, false, false, false, true><<<gN, blk, 0, stream>>>(
        node_feat, KIN, enc_nw, enc_nb, h,
        nullptr, nullptr, nullptr, nullptr, nullptr, nullptr, nullptr, nullptr,
        nullptr, nullptr, nullptr);

    for (int l = 0; l < 2; ++l) {
        hipMemsetAsync(num, 0, 2 * NH * sizeof(float), stream);      // num+den
        hipMemsetAsync(stats, 0, 1024 * sizeof(float), stream);
        const float* W  = lin_w + (size_t)l * 5 * HH * HH;
        const float* Bv = lin_b + (size_t)l * 5 * HH;

        // node linears A,B,D,E
        const int midx[4] = {0, 1, 3, 4};
        float* outp[4] = {Ah, Bh, Dh, Eh};
        for (int t = 0; t < 4; ++t) {
            gemm_k<A_PLAIN, false, false, false, true><<<gN, blk, 0, stream>>>(
                h, HH, W + (size_t)midx[t] * HH * HH, Bv + midx[t] * HH, outp[t],
                nullptr, nullptr, nullptr, nullptr, nullptr, nullptr, nullptr,
                nullptr, nullptr, nullptr, nullptr);
        }

        if (l == 0) {
            // e_new1 = (edge_enc on-the-fly) @ Wc + bc + Dh[src] + Eh[dst]
            gemm_k<A_EDGE, true, false, false, true><<<gE, blk, 0, stream>>>(
                nullptr, HH, W + 2 * HH * HH, Bv + 2 * HH, enew,
                edge_feat, enc_ew, enc_eb, nullptr, Dh, Eh, src, dst,
                nullptr, nullptr, nullptr);
            edge_post<<<NE / 512, blk, 0, stream>>>(
                enew, src, dst, Bh, num, den, stats + 256, stats + 384);
            make_bnp<<<1, 128, 0, stream>>>(
                stats + 256, stats + 384, bne_g, bne_b, 1.f / NE, bnp);
        } else {
            // fused: A = relu(bn(e_new1)); epilogue: sigmoid + atomics (no store)
            gemm_k<A_BN, true, true, false, false><<<gE, blk, 0, stream>>>(
                enew, HH, W + 2 * HH * HH, Bv + 2 * HH, nullptr,
                nullptr, nullptr, nullptr, bnp, Dh, Eh, src, dst,
                Bh, num, den);
        }

        h_stats<<<(NN + 255) / 256, blk, 0, stream>>>(
            Ah, num, den, hnew, stats, stats + 128);
        make_bnp<<<1, 128, 0, stream>>>(
            stats, stats + 128, bnh_g + l * HH, bnh_b + l * HH, 1.f / NN, bnp + 256);
        h_apply<<<(int)(NH / 4 / 256), blk, 0, stream>>>(hnew, bnp + 256, h);
    }

    // readout: z = relu(h @ mlp_w1 + mlp_b1); out = z @ mlp_w2 + mlp_b2
    gemm_k<A_PLAIN, false, false, true, true><<<gN, blk, 0, stream>>>(
        h, HH, mlp_w1, mlp_b1, z,
        nullptr, nullptr, nullptr, nullptr, nullptr, nullptr, nullptr, nullptr,
        nullptr, nullptr, nullptr);
    readout2<<<(NN * NCLS + 255) / 256, blk, 0, stream>>>(z, mlp_w2, mlp_b2, out);
}

// Round 3
// 1607.873 us; speedup vs baseline: 2.2223x; 2.2223x over previous
//
#include <hip/hip_runtime.h>
#include <math.h>

#define NN 40000
#define NE 640000
#define KIN 776
#define HH 128
#define NCLS 5

#define TM 64
#define TK 16

enum { A_PLAIN = 0, A_EDGE = 1, A_BN = 2 };

// Tiled f32 GEMM: C[M,128] = A[M,K] @ B[K,128] + bias. Each block owns a
// full 64x128 output panel (TN==HH==128), so in-place C==A is safe: all A
// reads of the block's rows complete (last __syncthreads) before any store,
// and no other block touches these rows.
// A-side modes: plain / edge-encoder-on-the-fly / BN+ReLU.
// Epilogue: optional gather Dh[src]+Eh[dst], BN column-stat partials, relu.
template<int AMODE, bool GATHER, bool ESTAT, bool RELUOUT, bool STOREC>
__global__ __launch_bounds__(256)
void gemm_k(const float* __restrict__ A, int K,
            const float* __restrict__ B, const float* __restrict__ bias,
            float* __restrict__ C,
            const float* __restrict__ ef, const float* __restrict__ eW,
            const float* __restrict__ eB, const float* __restrict__ bnp,
            const float* __restrict__ Dh, const float* __restrict__ Eh,
            const int* __restrict__ src, const int* __restrict__ dst,
            float* __restrict__ pbuf)
{
    __shared__ float As[TK][TM + 4];   // transposed A tile, padded
    __shared__ float Bs[TK][HH];
    const int tid = threadIdx.x;
    const int m0 = blockIdx.x * TM;
    const int tx = tid & 15, ty = tid >> 4;
    const int arow = tid >> 2, akc = (tid & 3) * 4;
    const int brow = tid >> 4, bcol = (tid & 15) * 8;

    float acc[4][8] = {};

    for (int kt = 0; kt < K; kt += TK) {
        // ---- A tile (64 rows x 16 k) ----
        float4 av;
        const int gr = m0 + arow;
        if (AMODE == A_EDGE) {
            const float f0 = ef[(size_t)gr * 2 + 0];
            const float f1 = ef[(size_t)gr * 2 + 1];
            const int k = kt + akc;
            const float4 w0 = *(const float4*)(eW + k);
            const float4 w1 = *(const float4*)(eW + HH + k);
            const float4 b4 = *(const float4*)(eB + k);
            av.x = fmaf(f0, w0.x, fmaf(f1, w1.x, b4.x));
            av.y = fmaf(f0, w0.y, fmaf(f1, w1.y, b4.y));
            av.z = fmaf(f0, w0.z, fmaf(f1, w1.z, b4.z));
            av.w = fmaf(f0, w0.w, fmaf(f1, w1.w, b4.w));
        } else {
            const int k = kt + akc;
            if (k + 3 < K) {
                av = *(const float4*)(A + (size_t)gr * K + k);
            } else {
                av.x = (k + 0 < K) ? A[(size_t)gr * K + k + 0] : 0.f;
                av.y = (k + 1 < K) ? A[(size_t)gr * K + k + 1] : 0.f;
                av.z = (k + 2 < K) ? A[(size_t)gr * K + k + 2] : 0.f;
                av.w = (k + 3 < K) ? A[(size_t)gr * K + k + 3] : 0.f;
            }
            if (AMODE == A_BN) {
                const float4 sc = *(const float4*)(bnp + k);
                const float4 sh = *(const float4*)(bnp + HH + k);
                av.x = fmaxf(fmaf(av.x, sc.x, sh.x), 0.f);
                av.y = fmaxf(fmaf(av.y, sc.y, sh.y), 0.f);
                av.z = fmaxf(fmaf(av.z, sc.z, sh.z), 0.f);
                av.w = fmaxf(fmaf(av.w, sc.w, sh.w), 0.f);
            }
        }
        As[akc + 0][arow] = av.x;
        As[akc + 1][arow] = av.y;
        As[akc + 2][arow] = av.z;
        As[akc + 3][arow] = av.w;

        // ---- B tile (16 k x 128 cols), 8 floats per thread ----
        {
            const int k = kt + brow;
            float4 bv0 = make_float4(0.f, 0.f, 0.f, 0.f);
            float4 bv1 = bv0;
            if (k < K) {
                bv0 = *(const float4*)(B + (size_t)k * HH + bcol);
                bv1 = *(const float4*)(B + (size_t)k * HH + bcol + 4);
            }
            *(float4*)&Bs[brow][bcol] = bv0;
            *(float4*)&Bs[brow][bcol + 4] = bv1;
        }
        __syncthreads();

        #pragma unroll
        for (int kk = 0; kk < TK; ++kk) {
            const float4 a4 = *(const float4*)&As[kk][ty * 4];
            const float4 b0 = *(const float4*)&Bs[kk][tx * 4];
            const float4 b1 = *(const float4*)&Bs[kk][64 + tx * 4];
            const float avr[4] = {a4.x, a4.y, a4.z, a4.w};
            const float bvr[8] = {b0.x, b0.y, b0.z, b0.w, b1.x, b1.y, b1.z, b1.w};
            #pragma unroll
            for (int i = 0; i < 4; ++i)
                #pragma unroll
                for (int j = 0; j < 8; ++j)
                    acc[i][j] = fmaf(avr[i], bvr[j], acc[i][j]);
        }
        __syncthreads();
    }

    const int c0 = tx * 4;        // cols c0..c0+3
    const int c1 = 64 + tx * 4;   // cols c1..c1+3
    const float4 bb0 = *(const float4*)(bias + c0);
    const float4 bb1 = *(const float4*)(bias + c1);
    const float biasv[8] = {bb0.x, bb0.y, bb0.z, bb0.w, bb1.x, bb1.y, bb1.z, bb1.w};
    float sa[8] = {}, qa[8] = {};
    #pragma unroll
    for (int i = 0; i < 4; ++i) {
        const int gr = m0 + ty * 4 + i;
        float v[8];
        #pragma unroll
        for (int j = 0; j < 8; ++j) v[j] = acc[i][j] + biasv[j];
        if (GATHER) {
            const int sI = src[gr], dI = dst[gr];
            const float4 d0 = *(const float4*)(Dh + (size_t)sI * HH + c0);
            const float4 d1 = *(const float4*)(Dh + (size_t)sI * HH + c1);
            const float4 e0 = *(const float4*)(Eh + (size_t)dI * HH + c0);
            const float4 e1 = *(const float4*)(Eh + (size_t)dI * HH + c1);
            v[0] += d0.x + e0.x; v[1] += d0.y + e0.y;
            v[2] += d0.z + e0.z; v[3] += d0.w + e0.w;
            v[4] += d1.x + e1.x; v[5] += d1.y + e1.y;
            v[6] += d1.z + e1.z; v[7] += d1.w + e1.w;
        }
        if (RELUOUT) {
            #pragma unroll
            for (int j = 0; j < 8; ++j) v[j] = fmaxf(v[j], 0.f);
        }
        if (ESTAT) {
            #pragma unroll
            for (int j = 0; j < 8; ++j) { sa[j] += v[j]; qa[j] += v[j] * v[j]; }
        }
        if (STOREC) {
            *(float4*)(C + (size_t)gr * HH + c0) = make_float4(v[0], v[1], v[2], v[3]);
            *(float4*)(C + (size_t)gr * HH + c1) = make_float4(v[4], v[5], v[6], v[7]);
        }
    }
    if constexpr (ESTAT) {
        __shared__ float sred[16][136];   // [ty][0..63: sum | 68..131: sq]
        const int slot = (blockIdx.x & 63) * 256;
        #pragma unroll
        for (int half = 0; half < 2; ++half) {
            const int cb = half ? c1 : c0;
            #pragma unroll
            for (int j = 0; j < 4; ++j) {
                sred[ty][tx * 4 + j] = sa[half * 4 + j];
                sred[ty][68 + tx * 4 + j] = qa[half * 4 + j];
            }
            __syncthreads();
            for (int s = 8; s > 0; s >>= 1) {
                if (ty < s) {
                    #pragma unroll
                    for (int j = 0; j < 4; ++j) {
                        sred[ty][tx * 4 + j] += sred[ty + s][tx * 4 + j];
                        sred[ty][68 + tx * 4 + j] += sred[ty + s][68 + tx * 4 + j];
                    }
                }
                __syncthreads();
            }
            if (ty == 0) {
                #pragma unroll
                for (int j = 0; j < 4; ++j) {
                    atomicAdd(pbuf + slot + cb + j, sred[0][tx * 4 + j]);
                    atomicAdd(pbuf + slot + 128 + cb + j, sred[0][68 + tx * 4 + j]);
                }
            }
            __syncthreads();
        }
    }
}

// ---- CSR build: histogram -> single-block scan -> scatter ----
__global__ __launch_bounds__(256)
void hist_k(const int* __restrict__ dst, int* __restrict__ cnt)
{
    const int e = blockIdx.x * 256 + threadIdx.x;
    if (e < NE) atomicAdd(cnt + dst[e], 1);
}

__global__ __launch_bounds__(1024)
void scan_k(const int* __restrict__ cnt, int* __restrict__ rowptr, int* __restrict__ wr)
{
    __shared__ int s[1024];
    const int t = threadIdx.x;
    const int base = t * 40;              // 1024*40 = 40960 >= NN
    int sum = 0;
    for (int i = 0; i < 40; ++i) {
        const int idx = base + i;
        if (idx < NN) sum += cnt[idx];
    }
    s[t] = sum;
    __syncthreads();
    for (int off = 1; off < 1024; off <<= 1) {
        const int v = (t >= off) ? s[t - off] : 0;
        __syncthreads();
        s[t] += v;
        __syncthreads();
    }
    int run = (t == 0) ? 0 : s[t - 1];
    for (int i = 0; i < 40; ++i) {
        const int idx = base + i;
        if (idx < NN) {
            rowptr[idx] = run;
            wr[idx] = run;
            run += cnt[idx];
        }
    }
    if (t == 1023) rowptr[NN] = s[1023];
}

__global__ __launch_bounds__(256)
void scatter_k(const int* __restrict__ dst, int* __restrict__ wr, int* __restrict__ eidx)
{
    const int e = blockIdx.x * 256 + threadIdx.x;
    if (e < NE) {
        const int p = atomicAdd(wr + dst[e], 1);
        eidx[p] = e;
    }
}

// Per-node CSR gather reduction: sigma = sigmoid(enew[e]), num/den in regs,
// hnew = Ah + num/(den+eps). No f32 atomics.
__global__ __launch_bounds__(128)
void seg_reduce(const float* __restrict__ enew, const int* __restrict__ eidx,
                const int* __restrict__ rowptr, const int* __restrict__ src,
                const float* __restrict__ Bh, const float* __restrict__ Ah,
                float* __restrict__ hnew)
{
    const int n = blockIdx.x;
    const int c = threadIdx.x;
    const int k0 = rowptr[n], k1 = rowptr[n + 1];
    float num = 0.f, den = 0.f;
    for (int k = k0; k < k1; ++k) {
        const int e = eidx[k];
        const float x = enew[(size_t)e * HH + c];
        const float sg = 1.f / (1.f + __expf(-x));
        const float bh = Bh[(size_t)src[e] * HH + c];
        den += sg;
        num = fmaf(sg, bh, num);
    }
    const size_t idx = (size_t)n * HH + c;
    hnew[idx] = Ah[idx] + num / (den + 1e-6f);
}

// Finish e-BN stats: esum/esq[j] = sum over 64 pbuf slots.
__global__ __launch_bounds__(256)
void estat_finish(const float* __restrict__ pbuf, float* __restrict__ es)
{
    const int j = threadIdx.x;            // 0..255 -> [esum(128) | esq(128)]
    float s = 0.f;
    for (int i = 0; i < 64; ++i) s += pbuf[i * 256 + j];
    es[j] = s;
}

// h-BN column stats from hnew.
__global__ __launch_bounds__(256)
void h_stats2(const float* __restrict__ hnew, float* __restrict__ hsum,
              float* __restrict__ hsq)
{
    const int tid = threadIdx.x;
    const int c = tid & 127, sub = tid >> 7;
    const int r0 = blockIdx.x * 256;
    float sa = 0.f, qa = 0.f;
    for (int i = sub; i < 256; i += 2) {
        const int r = r0 + i;
        if (r >= NN) break;
        const float x = hnew[(size_t)r * HH + c];
        sa += x; qa += x * x;
    }
    __shared__ float red[256];
    red[tid] = sa; __syncthreads();
    if (tid < 128) atomicAdd(hsum + c, red[tid] + red[tid + 128]);
    __syncthreads();
    red[tid] = qa; __syncthreads();
    if (tid < 128) atomicAdd(hsq + c, red[tid] + red[tid + 128]);
}

// BN params: scale = g*rsqrt(var+eps); shift = b - mean*scale.
__global__ void make_bnp(const float* __restrict__ sum, const float* __restrict__ sq,
                         const float* __restrict__ g, const float* __restrict__ b,
                         float cntInv, float* __restrict__ out)
{
    const int c = threadIdx.x;
    const float m = sum[c] * cntInv;
    const float var = sq[c] * cntInv - m * m;
    const float rs = rsqrtf(var + 1e-5f);
    const float sc = g[c] * rs;
    out[c] = sc;
    out[128 + c] = b[c] - m * sc;
}

// h = relu(hnew*scale + shift)
__global__ __launch_bounds__(256)
void h_apply(const float* __restrict__ hnew, const float* __restrict__ bnp,
             float* __restrict__ h)
{
    const int idx = blockIdx.x * 256 + threadIdx.x;   // float4 index
    const int c4 = (idx & 31) * 4;
    const float4 x = ((const float4*)hnew)[idx];
    const float4 sc = *(const float4*)(bnp + c4);
    const float4 sh = *(const float4*)(bnp + 128 + c4);
    float4 o;
    o.x = fmaxf(fmaf(x.x, sc.x, sh.x), 0.f);
    o.y = fmaxf(fmaf(x.y, sc.y, sh.y), 0.f);
    o.z = fmaxf(fmaf(x.z, sc.z, sh.z), 0.f);
    o.w = fmaxf(fmaf(x.w, sc.w, sh.w), 0.f);
    ((float4*)h)[idx] = o;
}

// logits = z @ mlp_w2 + mlp_b2  (z already relu'd)
__global__ __launch_bounds__(256)
void readout2(const float* __restrict__ z, const float* __restrict__ w2,
              const float* __restrict__ b2, float* __restrict__ out)
{
    const int idx = blockIdx.x * 256 + threadIdx.x;
    if (idx >= NN * NCLS) return;
    const int n = idx / NCLS, j = idx - n * NCLS;
    float acc = b2[j];
    const float* zr = z + (size_t)n * HH;
    for (int k = 0; k < HH; ++k) acc = fmaf(zr[k], w2[k * NCLS + j], acc);
    out[idx] = acc;
}

extern "C" void kernel_launch(void* const* d_in, const int* in_sizes, int n_in,
                              void* d_out, int out_size, void* d_ws, size_t ws_size,
                              hipStream_t stream)
{
    const float* node_feat = (const float*)d_in[0];
    const float* edge_feat = (const float*)d_in[1];
    const int*   src       = (const int*)d_in[2];
    const int*   dst       = (const int*)d_in[3];
    const float* enc_nw    = (const float*)d_in[4];
    const float* enc_nb    = (const float*)d_in[5];
    const float* enc_ew    = (const float*)d_in[6];
    const float* enc_eb    = (const float*)d_in[7];
    const float* lin_w     = (const float*)d_in[8];
    const float* lin_b     = (const float*)d_in[9];
    const float* bnh_g     = (const float*)d_in[10];
    const float* bnh_b     = (const float*)d_in[11];
    const float* bne_g     = (const float*)d_in[12];
    const float* bne_b     = (const float*)d_in[13];
    const float* mlp_w1    = (const float*)d_in[14];
    const float* mlp_b1    = (const float*)d_in[15];
    const float* mlp_w2    = (const float*)d_in[16];
    const float* mlp_b2    = (const float*)d_in[17];
    float* out = (float*)d_out;
    float* ws  = (float*)d_ws;

    const size_t NH = (size_t)NN * HH;   // 5,120,000 floats
    float* h     = ws;
    float* hnew  = ws + 1 * NH;
    float* Ah    = ws + 2 * NH;
    float* Bh    = ws + 3 * NH;
    float* Dh    = ws + 4 * NH;
    float* Eh    = ws + 5 * NH;
    float* stats = ws + 6 * NH;          // [hsum(128), hsq(128), esum(128), esq(128)]
    float* bnp   = stats + 1024;         // [ebnp(256), hbnp(256)]
    float* pbuf  = bnp + 512;            // 64 slots x 256
    int*   cnt    = (int*)(pbuf + 16384);
    int*   rowptr = cnt + NN;            // NN+1
    int*   wr     = rowptr + NN + 1;
    int*   eidx   = wr + NN;             // NE
    size_t off = (size_t)((float*)(eidx + NE) - ws);
    off = (off + 3) & ~(size_t)3;        // 16B-align for float4
    float* enew  = ws + off;             // E*H floats
    float* z     = hnew;                 // reuse for readout

    const dim3 blk(256);
    const dim3 gN(NN / TM);              // 625
    const dim3 gE(NE / TM);              // 10000

    // ---- CSR build (dst-sorted edge index) ----
    hipMemsetAsync(cnt, 0, NN * sizeof(int), stream);
    hipMemsetAsync(pbuf, 0, 16384 * sizeof(float), stream);
    hist_k<<<(NE + 255) / 256, blk, 0, stream>>>(dst, cnt);
    scan_k<<<1, 1024, 0, stream>>>(cnt, rowptr, wr);
    scatter_k<<<(NE + 255) / 256, blk, 0, stream>>>(dst, wr, eidx);

    // node encoder: h = node_feat @ enc_nw + enc_nb
    gemm_k<A_PLAIN, false, false, false, true><<<gN, blk, 0, stream>>>(
        node_feat, KIN, enc_nw, enc_nb, h,
        nullptr, nullptr, nullptr, nullptr, nullptr, nullptr, nullptr, nullptr,
        nullptr);

    for (int l = 0; l < 2; ++l) {
        hipMemsetAsync(stats, 0, 1024 * sizeof(float), stream);
        const float* W  = lin_w + (size_t)l * 5 * HH * HH;
        const float* Bv = lin_b + (size_t)l * 5 * HH;

        // node linears A,B,D,E
        const int midx[4] = {0, 1, 3, 4};
        float* outp[4] = {Ah, Bh, Dh, Eh};
        for (int t = 0; t < 4; ++t) {
            gemm_k<A_PLAIN, false, false, false, true><<<gN, blk, 0, stream>>>(
                h, HH, W + (size_t)midx[t] * HH * HH, Bv + midx[t] * HH, outp[t],
                nullptr, nullptr, nullptr, nullptr, nullptr, nullptr, nullptr,
                nullptr, nullptr);
        }

        if (l == 0) {
            // e_new1 = (edge_enc on-the-fly) @ Wc + bc + Dh[src] + Eh[dst]; + e-stats
            gemm_k<A_EDGE, true, true, false, true><<<gE, blk, 0, stream>>>(
                nullptr, HH, W + 2 * HH * HH, Bv + 2 * HH, enew,
                edge_feat, enc_ew, enc_eb, nullptr, Dh, Eh, src, dst, pbuf);
            estat_finish<<<1, 256, 0, stream>>>(pbuf, stats + 256);
            make_bnp<<<1, 128, 0, stream>>>(
                stats + 256, stats + 384, bne_g, bne_b, 1.f / NE, bnp);
        } else {
            // e_new2 = relu(bn(e_new1)) @ Wc + bc + Dh[src] + Eh[dst], in place.
            // Safe: one block per 64-row panel owns all 128 cols (see gemm_k).
            gemm_k<A_BN, true, false, false, true><<<gE, blk, 0, stream>>>(
                enew, HH, W + 2 * HH * HH, Bv + 2 * HH, enew,
                nullptr, nullptr, nullptr, bnp, Dh, Eh, src, dst, nullptr);
        }

        // per-node segment reduction + h_new
        seg_reduce<<<NN, 128, 0, stream>>>(enew, eidx, rowptr, src, Bh, Ah, hnew);
        h_stats2<<<(NN + 255) / 256, blk, 0, stream>>>(hnew, stats, stats + 128);
        make_bnp<<<1, 128, 0, stream>>>(
            stats, stats + 128, bnh_g + l * HH, bnh_b + l * HH, 1.f / NN, bnp + 256);
        h_apply<<<(int)(NH / 4 / 256), blk, 0, stream>>>(hnew, bnp + 256, h);
    }

    // readout: z = relu(h @ mlp_w1 + mlp_b1); out = z @ mlp_w2 + mlp_b2
    gemm_k<A_PLAIN, false, false, true, true><<<gN, blk, 0, stream>>>(
        h, HH, mlp_w1, mlp_b1, z,
        nullptr, nullptr, nullptr, nullptr, nullptr, nullptr, nullptr, nullptr,
        nullptr);
    readout2<<<(NN * NCLS + 255) / 256, blk, 0, stream>>>(z, mlp_w2, mlp_b2, out);
}

// Round 4
// 974.098 us; speedup vs baseline: 3.6682x; 1.6506x over previous
//
#include <hip/hip_runtime.h>
#include <math.h>

#define NN 40000
#define NE 640000
#define KIN 776
#define HH 128
#define NCLS 5

typedef __attribute__((ext_vector_type(8))) short bf16x8;
typedef __attribute__((ext_vector_type(4))) short bf16x4;
typedef __attribute__((ext_vector_type(4))) float f32x4;

__device__ __forceinline__ float bf2f(short u) {
    return __uint_as_float(((unsigned)(unsigned short)u) << 16);
}
__device__ __forceinline__ short f2bf(float f) {          // RNE
    unsigned u = __float_as_uint(f);
    u += 0x7fffu + ((u >> 16) & 1u);
    return (short)(u >> 16);
}

enum { A_F32 = 0, A_BF16 = 1, A_BN = 2 };

// MFMA GEMM: C[M,128] = op(A)[M,K] @ W[K,128] + bias (+ gathers / relu).
// Swapped-operand mfma_f32_16x16x32_bf16: first operand = packed W fragment
// (Wp[kb][col][8], kb=K/8), second = A-row fragment. Output mapping: lane
// holds C[row = blk*64+wave*16+(lane&15)][col = n*16+(lane>>4)*4+reg] -> one
// output row per lane (vector bias/store, single-row gathers).
// No LDS, no barriers; weights served from L1/L2.
// In-place C==A safe: each lane reads/writes only its own row; wave-lockstep
// issues all A loads before any store.
template<int AMODE, int NSTEP, bool TAIL8, bool GATHER, bool RELUOUT, bool CBF16>
__global__ __launch_bounds__(256)
void mfma_gemm(const float* __restrict__ Af, const short* __restrict__ Ab,
               const short* __restrict__ Wp, const float* __restrict__ bias,
               float* __restrict__ Cf, short* __restrict__ Cb,
               const float* __restrict__ bnp,
               const short* __restrict__ Dh, const short* __restrict__ Eh,
               const int* __restrict__ src, const int* __restrict__ dstv,
               int K)
{
    const int lane = threadIdx.x & 63;
    const int wave = threadIdx.x >> 6;
    const int q = lane >> 4;
    const int c16 = lane & 15;
    const int row = blockIdx.x * 64 + wave * 16 + c16;

    f32x4 acc[8];
#pragma unroll
    for (int n = 0; n < 8; ++n) acc[n] = (f32x4){0.f, 0.f, 0.f, 0.f};

    for (int kt = 0; kt < NSTEP; ++kt) {
        bf16x8 afrag;
        const int kbase = kt * 32 + q * 8;
        if (AMODE == A_BF16) {
            afrag = *(const bf16x8*)(Ab + (size_t)row * K + kbase);
        } else if (AMODE == A_F32) {
            if (!TAIL8 || kt < NSTEP - 1 || q == 0) {
                const float* p = Af + (size_t)row * K + kbase;
                const float4 x = *(const float4*)p;
                const float4 y = *(const float4*)(p + 4);
                afrag[0] = f2bf(x.x); afrag[1] = f2bf(x.y);
                afrag[2] = f2bf(x.z); afrag[3] = f2bf(x.w);
                afrag[4] = f2bf(y.x); afrag[5] = f2bf(y.y);
                afrag[6] = f2bf(y.z); afrag[7] = f2bf(y.w);
            } else {
#pragma unroll
                for (int j = 0; j < 8; ++j) afrag[j] = 0;
            }
        } else {  // A_BN: bf16 in, relu(x*scale+shift), bf16 frag out
            const bf16x8 raw = *(const bf16x8*)(Ab + (size_t)row * K + kbase);
            const float4 s0 = *(const float4*)(bnp + kbase);
            const float4 s1 = *(const float4*)(bnp + kbase + 4);
            const float4 t0 = *(const float4*)(bnp + HH + kbase);
            const float4 t1 = *(const float4*)(bnp + HH + kbase + 4);
            const float scv[8] = {s0.x, s0.y, s0.z, s0.w, s1.x, s1.y, s1.z, s1.w};
            const float shv[8] = {t0.x, t0.y, t0.z, t0.w, t1.x, t1.y, t1.z, t1.w};
#pragma unroll
            for (int j = 0; j < 8; ++j)
                afrag[j] = f2bf(fmaxf(fmaf(bf2f(raw[j]), scv[j], shv[j]), 0.f));
        }
        const int kb = kt * 4 + q;
#pragma unroll
        for (int n = 0; n < 8; ++n) {
            const bf16x8 wfrag =
                *(const bf16x8*)(Wp + (size_t)kb * 1024 + (n * 16 + c16) * 8);
            acc[n] = __builtin_amdgcn_mfma_f32_16x16x32_bf16(wfrag, afrag, acc[n], 0, 0, 0);
        }
    }

    int sI = 0, dI = 0;
    if (GATHER) { sI = src[row]; dI = dstv[row]; }
#pragma unroll
    for (int n = 0; n < 8; ++n) {
        const int col = n * 16 + q * 4;
        const float4 b4 = *(const float4*)(bias + col);
        float v[4] = {acc[n][0] + b4.x, acc[n][1] + b4.y,
                      acc[n][2] + b4.z, acc[n][3] + b4.w};
        if (GATHER) {
            const bf16x4 dh = *(const bf16x4*)(Dh + (size_t)sI * HH + col);
            const bf16x4 eh = *(const bf16x4*)(Eh + (size_t)dI * HH + col);
#pragma unroll
            for (int j = 0; j < 4; ++j) v[j] += bf2f(dh[j]) + bf2f(eh[j]);
        }
        if (RELUOUT) {
#pragma unroll
            for (int j = 0; j < 4; ++j) v[j] = fmaxf(v[j], 0.f);
        }
        if (CBF16) {
            bf16x4 o;
#pragma unroll
            for (int j = 0; j < 4; ++j) o[j] = f2bf(v[j]);
            *(bf16x4*)(Cb + (size_t)row * HH + col) = o;
        } else {
            *(float4*)(Cf + (size_t)row * HH + col) = make_float4(v[0], v[1], v[2], v[3]);
        }
    }
}

// Pack all weight matrices to bf16 fragments: Wp[kb][col][8] = W[kb*8+j][col].
// kb map: enc_nw 0..99 (97 real + 3 zero), l0 A/B/D/E @100/116/132/148,
// l1 A/B/C/D/E @164/180/196/212/228, mlp_w1 @244. Total 260 kb.
__global__ __launch_bounds__(256)
void prepack_k(const float* __restrict__ enc_nw, const float* __restrict__ lin_w,
               const float* __restrict__ mlp_w1, short* __restrict__ wp)
{
    const int t = blockIdx.x * 256 + threadIdx.x;
    if (t >= 260 * 128) return;
    const int kbg = t >> 7, col = t & 127;
    const int kb0[11]  = {0, 100, 116, 132, 148, 164, 180, 196, 212, 228, 244};
    const int psel[11] = {0, 1, 1, 1, 1, 1, 1, 1, 1, 1, 2};
    const int soff[11] = {0, 0 * 16384, 1 * 16384, 3 * 16384, 4 * 16384,
                          5 * 16384, 6 * 16384, 7 * 16384, 8 * 16384, 9 * 16384, 0};
    const int Ksrc[11] = {KIN, 128, 128, 128, 128, 128, 128, 128, 128, 128, 128};
    int e = 10;
    while (e > 0 && kbg < kb0[e]) --e;
    const float* base = (psel[e] == 0) ? enc_nw : ((psel[e] == 1) ? lin_w : mlp_w1);
    const int kbl = kbg - kb0[e];
    bf16x8 o;
#pragma unroll
    for (int j = 0; j < 8; ++j) {
        const int k = kbl * 8 + j;
        const float v = (k < Ksrc[e]) ? base[(size_t)soff[e] + (size_t)k * HH + col] : 0.f;
        o[j] = f2bf(v);
    }
    *(bf16x8*)(wp + (size_t)kbg * 1024 + col * 8) = o;
}

// Rank-2 collapse of layer-1 edge path: G0 = enc_ew[0]@Wc, G1 = enc_ew[1]@Wc,
// g0 = enc_eb@Wc + bc.   (e_new1 = f0*G0 + f1*G1 + g0 + Dh[src] + Eh[dst])
__global__ void gpre_k(const float* __restrict__ enc_ew, const float* __restrict__ enc_eb,
                       const float* __restrict__ Wc, const float* __restrict__ bc,
                       float* __restrict__ G)
{
    const int c = threadIdx.x;
    float a0 = 0.f, a1 = 0.f, ab = 0.f;
    for (int k = 0; k < HH; ++k) {
        const float w = Wc[k * HH + c];
        a0 = fmaf(enc_ew[k], w, a0);
        a1 = fmaf(enc_ew[HH + k], w, a1);
        ab = fmaf(enc_eb[k], w, ab);
    }
    G[c] = a0; G[HH + c] = a1; G[2 * HH + c] = ab + bc[c];
}

// Layer-1 edge pass (no GEMM): e_new1 + bf16 store + e-BN column stats.
// Block = 256 edges (16 edges x 16 colgroups, 16 iters), reg-accumulated stats.
__global__ __launch_bounds__(256)
void edge1_k(const float* __restrict__ ef, const float* __restrict__ G,
             const short* __restrict__ Dh, const short* __restrict__ Eh,
             const int* __restrict__ src, const int* __restrict__ dst,
             short* __restrict__ enew, float* __restrict__ pbuf)
{
    const int tid = threadIdx.x;
    const int er = tid >> 4, cg = tid & 15;
    const int col = cg * 8;
    const float4 g00 = *(const float4*)(G + col);
    const float4 g01 = *(const float4*)(G + col + 4);
    const float4 g10 = *(const float4*)(G + HH + col);
    const float4 g11 = *(const float4*)(G + HH + col + 4);
    const float4 gb0 = *(const float4*)(G + 2 * HH + col);
    const float4 gb1 = *(const float4*)(G + 2 * HH + col + 4);
    const float G0v[8] = {g00.x, g00.y, g00.z, g00.w, g01.x, g01.y, g01.z, g01.w};
    const float G1v[8] = {g10.x, g10.y, g10.z, g10.w, g11.x, g11.y, g11.z, g11.w};
    const float GBv[8] = {gb0.x, gb0.y, gb0.z, gb0.w, gb1.x, gb1.y, gb1.z, gb1.w};
    float sa[8] = {}, qa[8] = {};
    for (int it = 0; it < 16; ++it) {
        const int e = blockIdx.x * 256 + it * 16 + er;
        const float f0 = ef[(size_t)e * 2];
        const float f1 = ef[(size_t)e * 2 + 1];
        const int s = src[e], d = dst[e];
        const bf16x8 dh = *(const bf16x8*)(Dh + (size_t)s * HH + col);
        const bf16x8 eh = *(const bf16x8*)(Eh + (size_t)d * HH + col);
        bf16x8 o;
#pragma unroll
        for (int j = 0; j < 8; ++j) {
            const float v = fmaf(f0, G0v[j], fmaf(f1, G1v[j], GBv[j]))
                            + bf2f(dh[j]) + bf2f(eh[j]);
            sa[j] += v; qa[j] += v * v;
            o[j] = f2bf(v);
        }
        *(bf16x8*)(enew + (size_t)e * HH + col) = o;
    }
    __shared__ float sred[16][136];
    const int slot = (blockIdx.x & 63) * 256;
#pragma unroll
    for (int j = 0; j < 8; ++j) sred[er][col + j] = sa[j];
    __syncthreads();
    for (int s2 = 8; s2 > 0; s2 >>= 1) {
        if (er < s2)
#pragma unroll
            for (int j = 0; j < 8; ++j) sred[er][col + j] += sred[er + s2][col + j];
        __syncthreads();
    }
    if (er == 0)
#pragma unroll
        for (int j = 0; j < 8; ++j) atomicAdd(pbuf + slot + col + j, sred[0][col + j]);
    __syncthreads();
#pragma unroll
    for (int j = 0; j < 8; ++j) sred[er][col + j] = qa[j];
    __syncthreads();
    for (int s2 = 8; s2 > 0; s2 >>= 1) {
        if (er < s2)
#pragma unroll
            for (int j = 0; j < 8; ++j) sred[er][col + j] += sred[er + s2][col + j];
        __syncthreads();
    }
    if (er == 0)
#pragma unroll
        for (int j = 0; j < 8; ++j) atomicAdd(pbuf + slot + HH + col + j, sred[0][col + j]);
}

// ---- CSR build: histogram -> single-block scan -> scatter ----
__global__ __launch_bounds__(256)
void hist_k(const int* __restrict__ dst, int* __restrict__ cnt)
{
    const int e = blockIdx.x * 256 + threadIdx.x;
    if (e < NE) atomicAdd(cnt + dst[e], 1);
}

__global__ __launch_bounds__(1024)
void scan_k(const int* __restrict__ cnt, int* __restrict__ rowptr, int* __restrict__ wr)
{
    __shared__ int s[1024];
    const int t = threadIdx.x;
    const int base = t * 40;
    int sum = 0;
    for (int i = 0; i < 40; ++i) {
        const int idx = base + i;
        if (idx < NN) sum += cnt[idx];
    }
    s[t] = sum;
    __syncthreads();
    for (int off = 1; off < 1024; off <<= 1) {
        const int v = (t >= off) ? s[t - off] : 0;
        __syncthreads();
        s[t] += v;
        __syncthreads();
    }
    int run = (t == 0) ? 0 : s[t - 1];
    for (int i = 0; i < 40; ++i) {
        const int idx = base + i;
        if (idx < NN) {
            rowptr[idx] = run;
            wr[idx] = run;
            run += cnt[idx];
        }
    }
    if (t == 1023) rowptr[NN] = s[1023];
}

__global__ __launch_bounds__(256)
void scatter_k(const int* __restrict__ dst, int* __restrict__ wr, int* __restrict__ eidx)
{
    const int e = blockIdx.x * 256 + threadIdx.x;
    if (e < NE) {
        const int p = atomicAdd(wr + dst[e], 1);
        eidx[p] = e;
    }
}

// Per-node CSR reduction over bf16 enew/Bh: hnew = Ah + num/(den+eps).
__global__ __launch_bounds__(128)
void seg_reduce(const short* __restrict__ enew, const int* __restrict__ eidx,
                const int* __restrict__ rowptr, const int* __restrict__ src,
                const short* __restrict__ Bh, const float* __restrict__ Ah,
                float* __restrict__ hnew)
{
    const int n = blockIdx.x;
    const int c = threadIdx.x;
    const int k0 = rowptr[n], k1 = rowptr[n + 1];
    float num = 0.f, den = 0.f;
    for (int k = k0; k < k1; ++k) {
        const int e = eidx[k];
        const float x = bf2f(enew[(size_t)e * HH + c]);
        const float sg = 1.f / (1.f + __expf(-x));
        const float bh = bf2f(Bh[(size_t)src[e] * HH + c]);
        den += sg;
        num = fmaf(sg, bh, num);
    }
    const size_t idx = (size_t)n * HH + c;
    hnew[idx] = Ah[idx] + num / (den + 1e-6f);
}

__global__ __launch_bounds__(256)
void estat_finish(const float* __restrict__ pbuf, float* __restrict__ es)
{
    const int j = threadIdx.x;
    float s = 0.f;
    for (int i = 0; i < 64; ++i) s += pbuf[i * 256 + j];
    es[j] = s;
}

__global__ __launch_bounds__(256)
void h_stats2(const float* __restrict__ hnew, float* __restrict__ hsum,
              float* __restrict__ hsq)
{
    const int tid = threadIdx.x;
    const int c = tid & 127, sub = tid >> 7;
    const int r0 = blockIdx.x * 256;
    float sa = 0.f, qa = 0.f;
    for (int i = sub; i < 256; i += 2) {
        const int r = r0 + i;
        if (r >= NN) break;
        const float x = hnew[(size_t)r * HH + c];
        sa += x; qa += x * x;
    }
    __shared__ float red[256];
    red[tid] = sa; __syncthreads();
    if (tid < 128) atomicAdd(hsum + c, red[tid] + red[tid + 128]);
    __syncthreads();
    red[tid] = qa; __syncthreads();
    if (tid < 128) atomicAdd(hsq + c, red[tid] + red[tid + 128]);
}

__global__ void make_bnp(const float* __restrict__ sum, const float* __restrict__ sq,
                         const float* __restrict__ g, const float* __restrict__ b,
                         float cntInv, float* __restrict__ out)
{
    const int c = threadIdx.x;
    const float m = sum[c] * cntInv;
    const float var = sq[c] * cntInv - m * m;
    const float rs = rsqrtf(var + 1e-5f);
    const float sc = g[c] * rs;
    out[c] = sc;
    out[128 + c] = b[c] - m * sc;
}

// h(bf16) = relu(hnew*scale + shift); 8 elems per thread
__global__ __launch_bounds__(256)
void h_apply(const float* __restrict__ hnew, const float* __restrict__ bnp,
             short* __restrict__ h)
{
    const int idx = blockIdx.x * 256 + threadIdx.x;
    const int c8 = (idx & 15) * 8;
    const float4 x0 = *(const float4*)(hnew + (size_t)idx * 8);
    const float4 x1 = *(const float4*)(hnew + (size_t)idx * 8 + 4);
    const float4 s0 = *(const float4*)(bnp + c8);
    const float4 s1 = *(const float4*)(bnp + c8 + 4);
    const float4 t0 = *(const float4*)(bnp + HH + c8);
    const float4 t1 = *(const float4*)(bnp + HH + c8 + 4);
    const float xv[8] = {x0.x, x0.y, x0.z, x0.w, x1.x, x1.y, x1.z, x1.w};
    const float sv[8] = {s0.x, s0.y, s0.z, s0.w, s1.x, s1.y, s1.z, s1.w};
    const float tv[8] = {t0.x, t0.y, t0.z, t0.w, t1.x, t1.y, t1.z, t1.w};
    bf16x8 o;
#pragma unroll
    for (int j = 0; j < 8; ++j) o[j] = f2bf(fmaxf(fmaf(xv[j], sv[j], tv[j]), 0.f));
    *(bf16x8*)(h + (size_t)idx * 8) = o;
}

// logits = z(bf16) @ mlp_w2 + mlp_b2
__global__ __launch_bounds__(256)
void readout2(const short* __restrict__ z, const float* __restrict__ w2,
              const float* __restrict__ b2, float* __restrict__ out)
{
    const int idx = blockIdx.x * 256 + threadIdx.x;
    if (idx >= NN * NCLS) return;
    const int n = idx / NCLS, j = idx - n * NCLS;
    float acc = b2[j];
    const short* zr = z + (size_t)n * HH;
    for (int kk = 0; kk < 16; ++kk) {
        const bf16x8 zv = *(const bf16x8*)(zr + kk * 8);
#pragma unroll
        for (int j8 = 0; j8 < 8; ++j8)
            acc = fmaf(bf2f(zv[j8]), w2[(kk * 8 + j8) * NCLS + j], acc);
    }
    out[idx] = acc;
}

extern "C" void kernel_launch(void* const* d_in, const int* in_sizes, int n_in,
                              void* d_out, int out_size, void* d_ws, size_t ws_size,
                              hipStream_t stream)
{
    const float* node_feat = (const float*)d_in[0];
    const float* edge_feat = (const float*)d_in[1];
    const int*   src       = (const int*)d_in[2];
    const int*   dst       = (const int*)d_in[3];
    const float* enc_nw    = (const float*)d_in[4];
    const float* enc_nb    = (const float*)d_in[5];
    const float* enc_ew    = (const float*)d_in[6];
    const float* enc_eb    = (const float*)d_in[7];
    const float* lin_w     = (const float*)d_in[8];
    const float* lin_b     = (const float*)d_in[9];
    const float* bnh_g     = (const float*)d_in[10];
    const float* bnh_b     = (const float*)d_in[11];
    const float* bne_g     = (const float*)d_in[12];
    const float* bne_b     = (const float*)d_in[13];
    const float* mlp_w1    = (const float*)d_in[14];
    const float* mlp_b1    = (const float*)d_in[15];
    const float* mlp_w2    = (const float*)d_in[16];
    const float* mlp_b2    = (const float*)d_in[17];
    float* out = (float*)d_out;

    char* base = (char*)d_ws;
    size_t off = 0;
    auto alloc = [&](size_t bytes) -> void* {
        void* p = base + off;
        off = (off + bytes + 255) & ~(size_t)255;
        return p;
    };
    const size_t NH = (size_t)NN * HH;
    float* hnew  = (float*)alloc(NH * 4);
    float* Ah    = (float*)alloc(NH * 4);
    short* h     = (short*)alloc(NH * 2);
    short* Bh    = (short*)alloc(NH * 2);
    short* Dh    = (short*)alloc(NH * 2);
    short* Eh    = (short*)alloc(NH * 2);
    short* z     = (short*)alloc(NH * 2);
    short* enew  = (short*)alloc((size_t)NE * HH * 2);
    short* wpack = (short*)alloc((size_t)260 * 1024 * 2);
    float* G     = (float*)alloc(384 * 4);
    float* stats = (float*)alloc(1024 * 4);   // [hsum,hsq,esum,esq]
    float* bnpb  = (float*)alloc(512 * 4);    // [e scale|shift, h scale|shift]
    float* pbuf  = (float*)alloc(16384 * 4);
    int* cnt     = (int*)alloc(NN * 4);
    int* rowptr  = (int*)alloc((NN + 1) * 4);
    int* wr      = (int*)alloc(NN * 4);
    int* eidx    = (int*)alloc((size_t)NE * 4);

    const dim3 blk(256);

    // CSR + weight prepack + rank-2 edge-encoder fold
    hipMemsetAsync(cnt, 0, NN * 4, stream);
    hipMemsetAsync(pbuf, 0, 16384 * 4, stream);
    hist_k<<<2500, blk, 0, stream>>>(dst, cnt);
    scan_k<<<1, 1024, 0, stream>>>(cnt, rowptr, wr);
    scatter_k<<<2500, blk, 0, stream>>>(dst, wr, eidx);
    prepack_k<<<130, blk, 0, stream>>>(enc_nw, lin_w, mlp_w1, wpack);
    gpre_k<<<1, 128, 0, stream>>>(enc_ew, enc_eb, lin_w + 2 * 16384, lin_b + 2 * HH, G);

    // encoder: h = bf16(node_feat @ enc_nw + enc_nb)
    mfma_gemm<A_F32, 25, true, false, false, true><<<625, blk, 0, stream>>>(
        node_feat, nullptr, wpack, enc_nb, nullptr, h,
        nullptr, nullptr, nullptr, nullptr, nullptr, KIN);

    const int WB[2][4] = {{100, 116, 132, 148}, {164, 180, 212, 228}};
    for (int l = 0; l < 2; ++l) {
        hipMemsetAsync(stats, 0, 1024 * 4, stream);
        const float* Bv = lin_b + (size_t)l * 5 * HH;

        // node linears: Ah (f32), Bh/Dh/Eh (bf16)
        mfma_gemm<A_BF16, 4, false, false, false, false><<<625, blk, 0, stream>>>(
            nullptr, h, wpack + (size_t)WB[l][0] * 1024, Bv + 0 * HH, Ah, nullptr,
            nullptr, nullptr, nullptr, nullptr, nullptr, HH);
        mfma_gemm<A_BF16, 4, false, false, false, true><<<625, blk, 0, stream>>>(
            nullptr, h, wpack + (size_t)WB[l][1] * 1024, Bv + 1 * HH, nullptr, Bh,
            nullptr, nullptr, nullptr, nullptr, nullptr, HH);
        mfma_gemm<A_BF16, 4, false, false, false, true><<<625, blk, 0, stream>>>(
            nullptr, h, wpack + (size_t)WB[l][2] * 1024, Bv + 3 * HH, nullptr, Dh,
            nullptr, nullptr, nullptr, nullptr, nullptr, HH);
        mfma_gemm<A_BF16, 4, false, false, false, true><<<625, blk, 0, stream>>>(
            nullptr, h, wpack + (size_t)WB[l][3] * 1024, Bv + 4 * HH, nullptr, Eh,
            nullptr, nullptr, nullptr, nullptr, nullptr, HH);

        if (l == 0) {
            edge1_k<<<2500, blk, 0, stream>>>(edge_feat, G, Dh, Eh, src, dst, enew, pbuf);
            estat_finish<<<1, 256, 0, stream>>>(pbuf, stats + 256);
            make_bnp<<<1, 128, 0, stream>>>(
                stats + 256, stats + 384, bne_g, bne_b, 1.f / NE, bnpb);
        } else {
            // e_new2 = relu(bn(e_new1)) @ Wc + bc + Dh[src] + Eh[dst], in place
            mfma_gemm<A_BN, 4, false, true, false, true><<<10000, blk, 0, stream>>>(
                nullptr, enew, wpack + (size_t)196 * 1024, lin_b + (5 + 2) * HH,
                nullptr, enew, bnpb, Dh, Eh, src, dst, HH);
        }

        seg_reduce<<<NN, 128, 0, stream>>>(enew, eidx, rowptr, src, Bh, Ah, hnew);
        h_stats2<<<157, blk, 0, stream>>>(hnew, stats, stats + 128);
        make_bnp<<<1, 128, 0, stream>>>(
            stats, stats + 128, bnh_g + l * HH, bnh_b + l * HH, 1.f / NN, bnpb + 256);
        h_apply<<<2500, blk, 0, stream>>>(hnew, bnpb + 256, h);
    }

    // readout
    mfma_gemm<A_BF16, 4, false, false, true, true><<<625, blk, 0, stream>>>(
        nullptr, h, wpack + (size_t)244 * 1024, mlp_b1, nullptr, z,
        nullptr, nullptr, nullptr, nullptr, nullptr, HH);
    readout2<<<782, blk, 0, stream>>>(z, mlp_w2, mlp_b2, out);
}

// Round 5
// 881.566 us; speedup vs baseline: 4.0533x; 1.1050x over previous
//
#include <hip/hip_runtime.h>
#include <math.h>

#define NN 40000
#define NE 640000
#define KIN 776
#define HH 128
#define NCLS 5

typedef __attribute__((ext_vector_type(8))) short bf16x8;
typedef __attribute__((ext_vector_type(4))) short bf16x4;
typedef __attribute__((ext_vector_type(4))) float f32x4;

__device__ __forceinline__ float bf2f(short u) {
    return __uint_as_float(((unsigned)(unsigned short)u) << 16);
}
__device__ __forceinline__ short f2bf(float f) {          // RNE
    unsigned u = __float_as_uint(f);
    u += 0x7fffu + ((u >> 16) & 1u);
    return (short)(u >> 16);
}

enum { A_F32 = 0, A_BF16 = 1, A_BN = 2, A_BNF32 = 3 };

// MFMA GEMM: C[M,128] = op(A)[M,K] @ W[K,128] + bias (+ gathers / relu).
// Swapped-operand mfma_f32_16x16x32_bf16: first operand = packed W fragment
// (Wp[kb][col][8], kb=K/8), second = A-row fragment. Lane owns one output row.
// No LDS/barriers. In-place C==A safe (lane reads/writes only its own row).
template<int AMODE, int NSTEP, bool TAIL8, bool GATHER, bool RELUOUT, bool CBF16>
__global__ __launch_bounds__(256)
void mfma_gemm(const float* __restrict__ Af, const short* __restrict__ Ab,
               const short* __restrict__ Wp, const float* __restrict__ bias,
               float* __restrict__ Cf, short* __restrict__ Cb,
               const float* __restrict__ bnp,
               const short* __restrict__ Dh, const short* __restrict__ Eh,
               const int* __restrict__ src, const int* __restrict__ dstv,
               int K)
{
    const int lane = threadIdx.x & 63;
    const int wave = threadIdx.x >> 6;
    const int q = lane >> 4;
    const int c16 = lane & 15;
    const int row = blockIdx.x * 64 + wave * 16 + c16;

    f32x4 acc[8];
#pragma unroll
    for (int n = 0; n < 8; ++n) acc[n] = (f32x4){0.f, 0.f, 0.f, 0.f};

    for (int kt = 0; kt < NSTEP; ++kt) {
        bf16x8 afrag;
        const int kbase = kt * 32 + q * 8;
        if (AMODE == A_BF16) {
            afrag = *(const bf16x8*)(Ab + (size_t)row * K + kbase);
        } else if (AMODE == A_F32) {
            if (!TAIL8 || kt < NSTEP - 1 || q == 0) {
                const float* p = Af + (size_t)row * K + kbase;
                const float4 x = *(const float4*)p;
                const float4 y = *(const float4*)(p + 4);
                afrag[0] = f2bf(x.x); afrag[1] = f2bf(x.y);
                afrag[2] = f2bf(x.z); afrag[3] = f2bf(x.w);
                afrag[4] = f2bf(y.x); afrag[5] = f2bf(y.y);
                afrag[6] = f2bf(y.z); afrag[7] = f2bf(y.w);
            } else {
#pragma unroll
                for (int j = 0; j < 8; ++j) afrag[j] = 0;
            }
        } else if (AMODE == A_BN) {   // bf16 in, relu(x*sc+sh)
            const bf16x8 raw = *(const bf16x8*)(Ab + (size_t)row * K + kbase);
            const float4 s0 = *(const float4*)(bnp + kbase);
            const float4 s1 = *(const float4*)(bnp + kbase + 4);
            const float4 t0 = *(const float4*)(bnp + HH + kbase);
            const float4 t1 = *(const float4*)(bnp + HH + kbase + 4);
            const float scv[8] = {s0.x, s0.y, s0.z, s0.w, s1.x, s1.y, s1.z, s1.w};
            const float shv[8] = {t0.x, t0.y, t0.z, t0.w, t1.x, t1.y, t1.z, t1.w};
#pragma unroll
            for (int j = 0; j < 8; ++j)
                afrag[j] = f2bf(fmaxf(fmaf(bf2f(raw[j]), scv[j], shv[j]), 0.f));
        } else {                      // A_BNF32: f32 in, relu(x*sc+sh)
            const float* p = Af + (size_t)row * K + kbase;
            const float4 x = *(const float4*)p;
            const float4 y = *(const float4*)(p + 4);
            const float4 s0 = *(const float4*)(bnp + kbase);
            const float4 s1 = *(const float4*)(bnp + kbase + 4);
            const float4 t0 = *(const float4*)(bnp + HH + kbase);
            const float4 t1 = *(const float4*)(bnp + HH + kbase + 4);
            const float xv[8] = {x.x, x.y, x.z, x.w, y.x, y.y, y.z, y.w};
            const float scv[8] = {s0.x, s0.y, s0.z, s0.w, s1.x, s1.y, s1.z, s1.w};
            const float shv[8] = {t0.x, t0.y, t0.z, t0.w, t1.x, t1.y, t1.z, t1.w};
#pragma unroll
            for (int j = 0; j < 8; ++j)
                afrag[j] = f2bf(fmaxf(fmaf(xv[j], scv[j], shv[j]), 0.f));
        }
        const int kb = kt * 4 + q;
#pragma unroll
        for (int n = 0; n < 8; ++n) {
            const bf16x8 wfrag =
                *(const bf16x8*)(Wp + (size_t)kb * 1024 + (n * 16 + c16) * 8);
            acc[n] = __builtin_amdgcn_mfma_f32_16x16x32_bf16(wfrag, afrag, acc[n], 0, 0, 0);
        }
    }

    int sI = 0, dI = 0;
    if (GATHER) { sI = src[row]; dI = dstv[row]; }
#pragma unroll
    for (int n = 0; n < 8; ++n) {
        const int col = n * 16 + q * 4;
        const float4 b4 = *(const float4*)(bias + col);
        float v[4] = {acc[n][0] + b4.x, acc[n][1] + b4.y,
                      acc[n][2] + b4.z, acc[n][3] + b4.w};
        if (GATHER) {
            const bf16x4 dh = *(const bf16x4*)(Dh + (size_t)sI * HH + col);
            const bf16x4 eh = *(const bf16x4*)(Eh + (size_t)dI * HH + col);
#pragma unroll
            for (int j = 0; j < 4; ++j) v[j] += bf2f(dh[j]) + bf2f(eh[j]);
        }
        if (RELUOUT) {
#pragma unroll
            for (int j = 0; j < 4; ++j) v[j] = fmaxf(v[j], 0.f);
        }
        if (CBF16) {
            bf16x4 o;
#pragma unroll
            for (int j = 0; j < 4; ++j) o[j] = f2bf(v[j]);
            *(bf16x4*)(Cb + (size_t)row * HH + col) = o;
        } else {
            *(float4*)(Cf + (size_t)row * HH + col) = make_float4(v[0], v[1], v[2], v[3]);
        }
    }
}

// Fused 4 node linears: one A-fragment load feeds 4 weight matrices.
// t=0 -> Ah (f32), t=1 -> Bh, t=2 -> Dh, t=3 -> Eh (bf16).
// ABN=false: A = h0 (bf16 raw). ABN=true: A = relu(bn(hnew f32)).
template<bool ABN>
__global__ __launch_bounds__(256, 2)
void fused4_k(const short* __restrict__ hb, const float* __restrict__ hf,
              const float* __restrict__ bnp,
              const short* __restrict__ w0, const short* __restrict__ w1,
              const short* __restrict__ w2, const short* __restrict__ w3,
              const float* __restrict__ b0, const float* __restrict__ b1,
              const float* __restrict__ b2, const float* __restrict__ b3,
              float* __restrict__ Ah, short* __restrict__ Bh,
              short* __restrict__ Dh, short* __restrict__ Eh)
{
    const int lane = threadIdx.x & 63;
    const int wave = threadIdx.x >> 6;
    const int q = lane >> 4;
    const int c16 = lane & 15;
    const int row = blockIdx.x * 64 + wave * 16 + c16;

    f32x4 acc[4][8];
#pragma unroll
    for (int t = 0; t < 4; ++t)
#pragma unroll
        for (int n = 0; n < 8; ++n) acc[t][n] = (f32x4){0.f, 0.f, 0.f, 0.f};

    const short* const ws[4] = {w0, w1, w2, w3};
#pragma unroll
    for (int kt = 0; kt < 4; ++kt) {
        const int kbase = kt * 32 + q * 8;
        bf16x8 afrag;
        if (!ABN) {
            afrag = *(const bf16x8*)(hb + (size_t)row * HH + kbase);
        } else {
            const float* p = hf + (size_t)row * HH + kbase;
            const float4 x = *(const float4*)p;
            const float4 y = *(const float4*)(p + 4);
            const float4 s0 = *(const float4*)(bnp + kbase);
            const float4 s1 = *(const float4*)(bnp + kbase + 4);
            const float4 t0 = *(const float4*)(bnp + HH + kbase);
            const float4 t1 = *(const float4*)(bnp + HH + kbase + 4);
            const float xv[8] = {x.x, x.y, x.z, x.w, y.x, y.y, y.z, y.w};
            const float scv[8] = {s0.x, s0.y, s0.z, s0.w, s1.x, s1.y, s1.z, s1.w};
            const float shv[8] = {t0.x, t0.y, t0.z, t0.w, t1.x, t1.y, t1.z, t1.w};
#pragma unroll
            for (int j = 0; j < 8; ++j)
                afrag[j] = f2bf(fmaxf(fmaf(xv[j], scv[j], shv[j]), 0.f));
        }
        const int kb = kt * 4 + q;
#pragma unroll
        for (int t = 0; t < 4; ++t)
#pragma unroll
            for (int n = 0; n < 8; ++n) {
                const bf16x8 wfrag =
                    *(const bf16x8*)(ws[t] + (size_t)kb * 1024 + (n * 16 + c16) * 8);
                acc[t][n] = __builtin_amdgcn_mfma_f32_16x16x32_bf16(wfrag, afrag, acc[t][n], 0, 0, 0);
            }
    }

    const float* const bs[4] = {b0, b1, b2, b3};
#pragma unroll
    for (int t = 0; t < 4; ++t) {
#pragma unroll
        for (int n = 0; n < 8; ++n) {
            const int col = n * 16 + q * 4;
            const float4 b4 = *(const float4*)(bs[t] + col);
            const float v[4] = {acc[t][n][0] + b4.x, acc[t][n][1] + b4.y,
                                acc[t][n][2] + b4.z, acc[t][n][3] + b4.w};
            if (t == 0) {
                *(float4*)(Ah + (size_t)row * HH + col) = make_float4(v[0], v[1], v[2], v[3]);
            } else {
                bf16x4 o;
#pragma unroll
                for (int j = 0; j < 4; ++j) o[j] = f2bf(v[j]);
                short* dstp = (t == 1) ? Bh : ((t == 2) ? Dh : Eh);
                *(bf16x4*)(dstp + (size_t)row * HH + col) = o;
            }
        }
    }
}

// Pack all weight matrices to bf16 fragments: Wp[kb][col][8] = W[kb*8+j][col].
__global__ __launch_bounds__(256)
void prepack_k(const float* __restrict__ enc_nw, const float* __restrict__ lin_w,
               const float* __restrict__ mlp_w1, short* __restrict__ wp)
{
    const int t = blockIdx.x * 256 + threadIdx.x;
    if (t >= 260 * 128) return;
    const int kbg = t >> 7, col = t & 127;
    const int kb0[11]  = {0, 100, 116, 132, 148, 164, 180, 196, 212, 228, 244};
    const int psel[11] = {0, 1, 1, 1, 1, 1, 1, 1, 1, 1, 2};
    const int soff[11] = {0, 0 * 16384, 1 * 16384, 3 * 16384, 4 * 16384,
                          5 * 16384, 6 * 16384, 7 * 16384, 8 * 16384, 9 * 16384, 0};
    const int Ksrc[11] = {KIN, 128, 128, 128, 128, 128, 128, 128, 128, 128, 128};
    int e = 10;
    while (e > 0 && kbg < kb0[e]) --e;
    const float* base = (psel[e] == 0) ? enc_nw : ((psel[e] == 1) ? lin_w : mlp_w1);
    const int kbl = kbg - kb0[e];
    bf16x8 o;
#pragma unroll
    for (int j = 0; j < 8; ++j) {
        const int k = kbl * 8 + j;
        const float v = (k < Ksrc[e]) ? base[(size_t)soff[e] + (size_t)k * HH + col] : 0.f;
        o[j] = f2bf(v);
    }
    *(bf16x8*)(wp + (size_t)kbg * 1024 + col * 8) = o;
}

// Rank-2 collapse of layer-1 edge GEMM.
__global__ void gpre_k(const float* __restrict__ enc_ew, const float* __restrict__ enc_eb,
                       const float* __restrict__ Wc, const float* __restrict__ bc,
                       float* __restrict__ G)
{
    const int c = threadIdx.x;
    float a0 = 0.f, a1 = 0.f, ab = 0.f;
    for (int k = 0; k < HH; ++k) {
        const float w = Wc[k * HH + c];
        a0 = fmaf(enc_ew[k], w, a0);
        a1 = fmaf(enc_ew[HH + k], w, a1);
        ab = fmaf(enc_eb[k], w, ab);
    }
    G[c] = a0; G[HH + c] = a1; G[2 * HH + c] = ab + bc[c];
}

// Layer-1 edge pass in dst-sorted space: writes enew[i] contiguously,
// accumulates e-BN column stats into pbuf partials.
__global__ __launch_bounds__(256)
void edge1_k(const float* __restrict__ ef, const int* __restrict__ eidx,
             const int* __restrict__ src_s, const int* __restrict__ dst_s,
             const float* __restrict__ G,
             const short* __restrict__ Dh, const short* __restrict__ Eh,
             short* __restrict__ enew, float* __restrict__ pbuf)
{
    const int tid = threadIdx.x;
    const int er = tid >> 4, cg = tid & 15;
    const int col = cg * 8;
    const float4 g00 = *(const float4*)(G + col);
    const float4 g01 = *(const float4*)(G + col + 4);
    const float4 g10 = *(const float4*)(G + HH + col);
    const float4 g11 = *(const float4*)(G + HH + col + 4);
    const float4 gb0 = *(const float4*)(G + 2 * HH + col);
    const float4 gb1 = *(const float4*)(G + 2 * HH + col + 4);
    const float G0v[8] = {g00.x, g00.y, g00.z, g00.w, g01.x, g01.y, g01.z, g01.w};
    const float G1v[8] = {g10.x, g10.y, g10.z, g10.w, g11.x, g11.y, g11.z, g11.w};
    const float GBv[8] = {gb0.x, gb0.y, gb0.z, gb0.w, gb1.x, gb1.y, gb1.z, gb1.w};
    float sa[8] = {}, qa[8] = {};
    for (int it = 0; it < 16; ++it) {
        const int i = blockIdx.x * 256 + it * 16 + er;
        const int e = eidx[i];
        const float f0 = ef[(size_t)e * 2];
        const float f1 = ef[(size_t)e * 2 + 1];
        const int s = src_s[i], d = dst_s[i];
        const bf16x8 dh = *(const bf16x8*)(Dh + (size_t)s * HH + col);
        const bf16x8 eh = *(const bf16x8*)(Eh + (size_t)d * HH + col);
        bf16x8 o;
#pragma unroll
        for (int j = 0; j < 8; ++j) {
            const float v = fmaf(f0, G0v[j], fmaf(f1, G1v[j], GBv[j]))
                            + bf2f(dh[j]) + bf2f(eh[j]);
            sa[j] += v; qa[j] += v * v;
            o[j] = f2bf(v);
        }
        *(bf16x8*)(enew + (size_t)i * HH + col) = o;
    }
    __shared__ float sred[16][136];
    const int slot = (blockIdx.x & 63) * 256;
#pragma unroll
    for (int j = 0; j < 8; ++j) sred[er][col + j] = sa[j];
    __syncthreads();
    for (int s2 = 8; s2 > 0; s2 >>= 1) {
        if (er < s2)
#pragma unroll
            for (int j = 0; j < 8; ++j) sred[er][col + j] += sred[er + s2][col + j];
        __syncthreads();
    }
    if (er == 0)
#pragma unroll
        for (int j = 0; j < 8; ++j) atomicAdd(pbuf + slot + col + j, sred[0][col + j]);
    __syncthreads();
#pragma unroll
    for (int j = 0; j < 8; ++j) sred[er][col + j] = qa[j];
    __syncthreads();
    for (int s2 = 8; s2 > 0; s2 >>= 1) {
        if (er < s2)
#pragma unroll
            for (int j = 0; j < 8; ++j) sred[er][col + j] += sred[er + s2][col + j];
        __syncthreads();
    }
    if (er == 0)
#pragma unroll
        for (int j = 0; j < 8; ++j) atomicAdd(pbuf + slot + 128 + col + j, sred[0][col + j]);
}

// ---- CSR build ----
__global__ __launch_bounds__(256)
void hist_k(const int* __restrict__ dst, int* __restrict__ cnt)
{
    const int e = blockIdx.x * 256 + threadIdx.x;
    if (e < NE) atomicAdd(cnt + dst[e], 1);
}

__global__ __launch_bounds__(1024)
void scan_k(const int* __restrict__ cnt, int* __restrict__ rowptr, int* __restrict__ wr)
{
    __shared__ int s[1024];
    const int t = threadIdx.x;
    const int base = t * 40;
    int sum = 0;
    for (int i = 0; i < 40; ++i) {
        const int idx = base + i;
        if (idx < NN) sum += cnt[idx];
    }
    s[t] = sum;
    __syncthreads();
    for (int off = 1; off < 1024; off <<= 1) {
        const int v = (t >= off) ? s[t - off] : 0;
        __syncthreads();
        s[t] += v;
        __syncthreads();
    }
    int run = (t == 0) ? 0 : s[t - 1];
    for (int i = 0; i < 40; ++i) {
        const int idx = base + i;
        if (idx < NN) {
            rowptr[idx] = run;
            wr[idx] = run;
            run += cnt[idx];
        }
    }
    if (t == 1023) rowptr[NN] = s[1023];
}

__global__ __launch_bounds__(256)
void scatter_k2(const int* __restrict__ dst, const int* __restrict__ src,
                int* __restrict__ wr, int* __restrict__ eidx,
                int* __restrict__ src_s, int* __restrict__ dst_s)
{
    const int e = blockIdx.x * 256 + threadIdx.x;
    if (e < NE) {
        const int d = dst[e];
        const int p = atomicAdd(wr + d, 1);
        eidx[p] = e;
        src_s[p] = src[e];
        dst_s[p] = d;
    }
}

// 8 nodes/block; contiguous sorted enew rows; fused h-BN stat partials.
__global__ __launch_bounds__(128)
void seg_reduce8(const short* __restrict__ enew, const int* __restrict__ rowptr,
                 const int* __restrict__ src_s, const short* __restrict__ Bh,
                 const float* __restrict__ Ah, float* __restrict__ hnew,
                 float* __restrict__ pbuf)
{
    const int c = threadIdx.x;
    const int nb = blockIdx.x * 8;
    float sa = 0.f, qa = 0.f;
    for (int nn = 0; nn < 8; ++nn) {
        const int n = nb + nn;
        const int k0 = rowptr[n], k1 = rowptr[n + 1];
        float num = 0.f, den = 0.f;
        for (int k = k0; k < k1; ++k) {
            const float x = bf2f(enew[(size_t)k * HH + c]);
            const float sg = 1.f / (1.f + __expf(-x));
            const float bh = bf2f(Bh[(size_t)src_s[k] * HH + c]);
            den += sg;
            num = fmaf(sg, bh, num);
        }
        const size_t idx = (size_t)n * HH + c;
        const float x = Ah[idx] + num / (den + 1e-6f);
        hnew[idx] = x;
        sa += x; qa += x * x;
    }
    const int slot = (blockIdx.x & 63) * 256;
    atomicAdd(pbuf + slot + c, sa);
    atomicAdd(pbuf + slot + 128 + c, qa);
}

// BN params from 64-slot partials: scale = g*rsqrt(var+eps); shift = b - mean*scale.
__global__ void make_bnp2(const float* __restrict__ pbuf, const float* __restrict__ g,
                          const float* __restrict__ b, float cntInv,
                          float* __restrict__ out)
{
    const int c = threadIdx.x;
    float s = 0.f, q = 0.f;
    for (int i = 0; i < 64; ++i) {
        s += pbuf[i * 256 + c];
        q += pbuf[i * 256 + 128 + c];
    }
    const float m = s * cntInv;
    const float var = q * cntInv - m * m;
    const float rs = rsqrtf(var + 1e-5f);
    const float sc = g[c] * rs;
    out[c] = sc;
    out[128 + c] = b[c] - m * sc;
}

// logits = z(bf16) @ mlp_w2 + mlp_b2
__global__ __launch_bounds__(256)
void readout2(const short* __restrict__ z, const float* __restrict__ w2,
              const float* __restrict__ b2, float* __restrict__ out)
{
    const int idx = blockIdx.x * 256 + threadIdx.x;
    if (idx >= NN * NCLS) return;
    const int n = idx / NCLS, j = idx - n * NCLS;
    float acc = b2[j];
    const short* zr = z + (size_t)n * HH;
    for (int kk = 0; kk < 16; ++kk) {
        const bf16x8 zv = *(const bf16x8*)(zr + kk * 8);
#pragma unroll
        for (int j8 = 0; j8 < 8; ++j8)
            acc = fmaf(bf2f(zv[j8]), w2[(kk * 8 + j8) * NCLS + j], acc);
    }
    out[idx] = acc;
}

extern "C" void kernel_launch(void* const* d_in, const int* in_sizes, int n_in,
                              void* d_out, int out_size, void* d_ws, size_t ws_size,
                              hipStream_t stream)
{
    const float* node_feat = (const float*)d_in[0];
    const float* edge_feat = (const float*)d_in[1];
    const int*   src       = (const int*)d_in[2];
    const int*   dst       = (const int*)d_in[3];
    const float* enc_nw    = (const float*)d_in[4];
    const float* enc_nb    = (const float*)d_in[5];
    const float* enc_ew    = (const float*)d_in[6];
    const float* enc_eb    = (const float*)d_in[7];
    const float* lin_w     = (const float*)d_in[8];
    const float* lin_b     = (const float*)d_in[9];
    const float* bnh_g     = (const float*)d_in[10];
    const float* bnh_b     = (const float*)d_in[11];
    const float* bne_g     = (const float*)d_in[12];
    const float* bne_b     = (const float*)d_in[13];
    const float* mlp_w1    = (const float*)d_in[14];
    const float* mlp_b1    = (const float*)d_in[15];
    const float* mlp_w2    = (const float*)d_in[16];
    const float* mlp_b2    = (const float*)d_in[17];
    float* out = (float*)d_out;

    char* base = (char*)d_ws;
    size_t off = 0;
    auto alloc = [&](size_t bytes) -> void* {
        void* p = base + off;
        off = (off + bytes + 255) & ~(size_t)255;
        return p;
    };
    const size_t NH = (size_t)NN * HH;
    float* hnew  = (float*)alloc(NH * 4);
    float* Ah    = (float*)alloc(NH * 4);
    short* h0    = (short*)alloc(NH * 2);
    short* Bh    = (short*)alloc(NH * 2);
    short* Dh    = (short*)alloc(NH * 2);
    short* Eh    = (short*)alloc(NH * 2);
    short* z     = (short*)alloc(NH * 2);
    short* enew  = (short*)alloc((size_t)NE * HH * 2);
    short* wpack = (short*)alloc((size_t)260 * 1024 * 2);
    float* G     = (float*)alloc(384 * 4);
    float* bnpe  = (float*)alloc(256 * 4);
    float* bnph  = (float*)alloc(256 * 4);
    float* pbe   = (float*)alloc(16384 * 4);
    float* pbh0  = (float*)alloc(16384 * 4);
    float* pbh1  = (float*)alloc(16384 * 4);
    int* cnt     = (int*)alloc(NN * 4);
    int* rowptr  = (int*)alloc((NN + 1) * 4);
    int* wr      = (int*)alloc(NN * 4);
    int* eidx    = (int*)alloc((size_t)NE * 4);
    int* src_s   = (int*)alloc((size_t)NE * 4);
    int* dst_s   = (int*)alloc((size_t)NE * 4);

    const dim3 blk(256);

    hipMemsetAsync(cnt, 0, NN * 4, stream);
    hipMemsetAsync(pbe, 0, 3 * 16384 * 4, stream);   // pbe,pbh0,pbh1 contiguous
    hist_k<<<2500, blk, 0, stream>>>(dst, cnt);
    scan_k<<<1, 1024, 0, stream>>>(cnt, rowptr, wr);
    scatter_k2<<<2500, blk, 0, stream>>>(dst, src, wr, eidx, src_s, dst_s);
    prepack_k<<<130, blk, 0, stream>>>(enc_nw, lin_w, mlp_w1, wpack);
    gpre_k<<<1, 128, 0, stream>>>(enc_ew, enc_eb, lin_w + 2 * 16384, lin_b + 2 * HH, G);

    // encoder: h0 = bf16(node_feat @ enc_nw + enc_nb)
    mfma_gemm<A_F32, 25, true, false, false, true><<<625, blk, 0, stream>>>(
        node_feat, nullptr, wpack, enc_nb, nullptr, h0,
        nullptr, nullptr, nullptr, nullptr, nullptr, KIN);

    // ---- layer 0 ----
    {
        const float* Bv = lin_b;
        fused4_k<false><<<625, blk, 0, stream>>>(
            h0, nullptr, nullptr,
            wpack + (size_t)100 * 1024, wpack + (size_t)116 * 1024,
            wpack + (size_t)132 * 1024, wpack + (size_t)148 * 1024,
            Bv + 0 * HH, Bv + 1 * HH, Bv + 3 * HH, Bv + 4 * HH,
            Ah, Bh, Dh, Eh);
        edge1_k<<<2500, blk, 0, stream>>>(edge_feat, eidx, src_s, dst_s, G,
                                          Dh, Eh, enew, pbe);
        make_bnp2<<<1, 128, 0, stream>>>(pbe, bne_g, bne_b, 1.f / NE, bnpe);
        seg_reduce8<<<5000, 128, 0, stream>>>(enew, rowptr, src_s, Bh, Ah, hnew, pbh0);
        make_bnp2<<<1, 128, 0, stream>>>(pbh0, bnh_g, bnh_b, 1.f / NN, bnph);
    }

    // ---- layer 1 ----
    {
        const float* Bv = lin_b + 5 * HH;
        fused4_k<true><<<625, blk, 0, stream>>>(
            nullptr, hnew, bnph,
            wpack + (size_t)164 * 1024, wpack + (size_t)180 * 1024,
            wpack + (size_t)212 * 1024, wpack + (size_t)228 * 1024,
            Bv + 0 * HH, Bv + 1 * HH, Bv + 3 * HH, Bv + 4 * HH,
            Ah, Bh, Dh, Eh);
        // e_new2 = relu(bn(e_new1)) @ Wc + bc + Dh[src] + Eh[dst], in place, sorted
        mfma_gemm<A_BN, 4, false, true, false, true><<<10000, blk, 0, stream>>>(
            nullptr, enew, wpack + (size_t)196 * 1024, Bv + 2 * HH,
            nullptr, enew, bnpe, Dh, Eh, src_s, dst_s, HH);
        seg_reduce8<<<5000, 128, 0, stream>>>(enew, rowptr, src_s, Bh, Ah, hnew, pbh1);
        make_bnp2<<<1, 128, 0, stream>>>(pbh1, bnh_g + HH, bnh_b + HH, 1.f / NN, bnph);
    }

    // readout: z = relu(relu(bn(hnew)) @ mlp_w1 + mlp_b1); out = z @ mlp_w2 + mlp_b2
    mfma_gemm<A_BNF32, 4, false, false, true, true><<<625, blk, 0, stream>>>(
        hnew, nullptr, wpack + (size_t)244 * 1024, mlp_b1, nullptr, z,
        bnph, nullptr, nullptr, nullptr, nullptr, HH);
    readout2<<<782, blk, 0, stream>>>(z, mlp_w2, mlp_b2, out);
}

// Round 6
// 816.005 us; speedup vs baseline: 4.3789x; 1.0803x over previous
//
#include <hip/hip_runtime.h>
#include <math.h>

#define NN 40000
#define NE 640000
#define KIN 776
#define HH 128
#define NCLS 5

typedef __attribute__((ext_vector_type(8))) short bf16x8;
typedef __attribute__((ext_vector_type(4))) short bf16x4;
typedef __attribute__((ext_vector_type(4))) float f32x4;

__device__ __forceinline__ float bf2f(short u) {
    return __uint_as_float(((unsigned)(unsigned short)u) << 16);
}
__device__ __forceinline__ short f2bf(float f) {          // RNE
    unsigned u = __float_as_uint(f);
    u += 0x7fffu + ((u >> 16) & 1u);
    return (short)(u >> 16);
}

enum { A_F32 = 0 };

// MFMA GEMM (encoder only now): C[M,128] = f32A[M,K] @ W[K,128] + bias -> bf16.
template<int NSTEP, bool TAIL8>
__global__ __launch_bounds__(256)
void mfma_gemm(const float* __restrict__ Af, const short* __restrict__ Wp,
               const float* __restrict__ bias, short* __restrict__ Cb, int K)
{
    const int lane = threadIdx.x & 63;
    const int wave = threadIdx.x >> 6;
    const int q = lane >> 4;
    const int c16 = lane & 15;
    const int row = blockIdx.x * 64 + wave * 16 + c16;

    f32x4 acc[8];
#pragma unroll
    for (int n = 0; n < 8; ++n) acc[n] = (f32x4){0.f, 0.f, 0.f, 0.f};

    for (int kt = 0; kt < NSTEP; ++kt) {
        bf16x8 afrag;
        const int kbase = kt * 32 + q * 8;
        if (!TAIL8 || kt < NSTEP - 1 || q == 0) {
            const float* p = Af + (size_t)row * K + kbase;
            const float4 x = *(const float4*)p;
            const float4 y = *(const float4*)(p + 4);
            afrag[0] = f2bf(x.x); afrag[1] = f2bf(x.y);
            afrag[2] = f2bf(x.z); afrag[3] = f2bf(x.w);
            afrag[4] = f2bf(y.x); afrag[5] = f2bf(y.y);
            afrag[6] = f2bf(y.z); afrag[7] = f2bf(y.w);
        } else {
#pragma unroll
            for (int j = 0; j < 8; ++j) afrag[j] = 0;
        }
        const int kb = kt * 4 + q;
#pragma unroll
        for (int n = 0; n < 8; ++n) {
            const bf16x8 wfrag =
                *(const bf16x8*)(Wp + (size_t)kb * 1024 + (n * 16 + c16) * 8);
            acc[n] = __builtin_amdgcn_mfma_f32_16x16x32_bf16(wfrag, afrag, acc[n], 0, 0, 0);
        }
    }
#pragma unroll
    for (int n = 0; n < 8; ++n) {
        const int col = n * 16 + q * 4;
        const float4 b4 = *(const float4*)(bias + col);
        bf16x4 o;
        o[0] = f2bf(acc[n][0] + b4.x); o[1] = f2bf(acc[n][1] + b4.y);
        o[2] = f2bf(acc[n][2] + b4.z); o[3] = f2bf(acc[n][3] + b4.w);
        *(bf16x4*)(Cb + (size_t)row * HH + col) = o;
    }
}

// Layer-2 edge GEMM, in-place on enew (dst-sorted space), 2 rows per lane.
// acc initialized with bias + Dh[src] + Eh[dst] (gathers issued pre-K-loop so
// MFMA hides their latency). A-side: relu(bn(enew)) on the fly.
__global__ __launch_bounds__(256)
void edge2_k(short* __restrict__ enew, const short* __restrict__ Wp,
             const float* __restrict__ bias, const float* __restrict__ bnp,
             const short* __restrict__ Dh, const short* __restrict__ Eh,
             const int* __restrict__ src_s, const int* __restrict__ dst_s)
{
    const int lane = threadIdx.x & 63;
    const int wave = threadIdx.x >> 6;
    const int q = lane >> 4;
    const int c16 = lane & 15;
    const int row0 = blockIdx.x * 128 + wave * 16 + c16;
    const int row1 = row0 + 64;

    const int s0 = src_s[row0], d0 = dst_s[row0];
    const int s1 = src_s[row1], d1 = dst_s[row1];

    f32x4 acc[2][8];
#pragma unroll
    for (int n = 0; n < 8; ++n) {
        const int col = n * 16 + q * 4;
        const float4 b4 = *(const float4*)(bias + col);
        const bf16x4 dh0 = *(const bf16x4*)(Dh + (size_t)s0 * HH + col);
        const bf16x4 eh0 = *(const bf16x4*)(Eh + (size_t)d0 * HH + col);
        const bf16x4 dh1 = *(const bf16x4*)(Dh + (size_t)s1 * HH + col);
        const bf16x4 eh1 = *(const bf16x4*)(Eh + (size_t)d1 * HH + col);
        const float bb[4] = {b4.x, b4.y, b4.z, b4.w};
#pragma unroll
        for (int j = 0; j < 4; ++j) {
            acc[0][n][j] = bb[j] + bf2f(dh0[j]) + bf2f(eh0[j]);
            acc[1][n][j] = bb[j] + bf2f(dh1[j]) + bf2f(eh1[j]);
        }
    }

#pragma unroll
    for (int kt = 0; kt < 4; ++kt) {
        const int kbase = kt * 32 + q * 8;
        const float4 sc0 = *(const float4*)(bnp + kbase);
        const float4 sc1 = *(const float4*)(bnp + kbase + 4);
        const float4 sh0 = *(const float4*)(bnp + HH + kbase);
        const float4 sh1 = *(const float4*)(bnp + HH + kbase + 4);
        const float scv[8] = {sc0.x, sc0.y, sc0.z, sc0.w, sc1.x, sc1.y, sc1.z, sc1.w};
        const float shv[8] = {sh0.x, sh0.y, sh0.z, sh0.w, sh1.x, sh1.y, sh1.z, sh1.w};
        const bf16x8 r0 = *(const bf16x8*)(enew + (size_t)row0 * HH + kbase);
        const bf16x8 r1 = *(const bf16x8*)(enew + (size_t)row1 * HH + kbase);
        bf16x8 a0, a1;
#pragma unroll
        for (int j = 0; j < 8; ++j) {
            a0[j] = f2bf(fmaxf(fmaf(bf2f(r0[j]), scv[j], shv[j]), 0.f));
            a1[j] = f2bf(fmaxf(fmaf(bf2f(r1[j]), scv[j], shv[j]), 0.f));
        }
        const int kb = kt * 4 + q;
#pragma unroll
        for (int n = 0; n < 8; ++n) {
            const bf16x8 wfrag =
                *(const bf16x8*)(Wp + (size_t)kb * 1024 + (n * 16 + c16) * 8);
            acc[0][n] = __builtin_amdgcn_mfma_f32_16x16x32_bf16(wfrag, a0, acc[0][n], 0, 0, 0);
            acc[1][n] = __builtin_amdgcn_mfma_f32_16x16x32_bf16(wfrag, a1, acc[1][n], 0, 0, 0);
        }
    }

#pragma unroll
    for (int n = 0; n < 8; ++n) {
        const int col = n * 16 + q * 4;
        bf16x4 o0, o1;
#pragma unroll
        for (int j = 0; j < 4; ++j) {
            o0[j] = f2bf(acc[0][n][j]);
            o1[j] = f2bf(acc[1][n][j]);
        }
        *(bf16x4*)(enew + (size_t)row0 * HH + col) = o0;
        *(bf16x4*)(enew + (size_t)row1 * HH + col) = o1;
    }
}

// Fused 4 node linears: one A-fragment load feeds 4 weight matrices.
// ABN=false: A = h0 (bf16). ABN=true: A = relu(bn(hnew f32)).
template<bool ABN>
__global__ __launch_bounds__(256, 2)
void fused4_k(const short* __restrict__ hb, const float* __restrict__ hf,
              const float* __restrict__ bnp,
              const short* __restrict__ w0, const short* __restrict__ w1,
              const short* __restrict__ w2, const short* __restrict__ w3,
              const float* __restrict__ b0, const float* __restrict__ b1,
              const float* __restrict__ b2, const float* __restrict__ b3,
              float* __restrict__ Ah, short* __restrict__ Bh,
              short* __restrict__ Dh, short* __restrict__ Eh)
{
    const int lane = threadIdx.x & 63;
    const int wave = threadIdx.x >> 6;
    const int q = lane >> 4;
    const int c16 = lane & 15;
    const int row = blockIdx.x * 64 + wave * 16 + c16;

    f32x4 acc[4][8];
#pragma unroll
    for (int t = 0; t < 4; ++t)
#pragma unroll
        for (int n = 0; n < 8; ++n) acc[t][n] = (f32x4){0.f, 0.f, 0.f, 0.f};

    const short* const ws[4] = {w0, w1, w2, w3};
#pragma unroll
    for (int kt = 0; kt < 4; ++kt) {
        const int kbase = kt * 32 + q * 8;
        bf16x8 afrag;
        if (!ABN) {
            afrag = *(const bf16x8*)(hb + (size_t)row * HH + kbase);
        } else {
            const float* p = hf + (size_t)row * HH + kbase;
            const float4 x = *(const float4*)p;
            const float4 y = *(const float4*)(p + 4);
            const float4 s0 = *(const float4*)(bnp + kbase);
            const float4 s1 = *(const float4*)(bnp + kbase + 4);
            const float4 t0 = *(const float4*)(bnp + HH + kbase);
            const float4 t1 = *(const float4*)(bnp + HH + kbase + 4);
            const float xv[8] = {x.x, x.y, x.z, x.w, y.x, y.y, y.z, y.w};
            const float scv[8] = {s0.x, s0.y, s0.z, s0.w, s1.x, s1.y, s1.z, s1.w};
            const float shv[8] = {t0.x, t0.y, t0.z, t0.w, t1.x, t1.y, t1.z, t1.w};
#pragma unroll
            for (int j = 0; j < 8; ++j)
                afrag[j] = f2bf(fmaxf(fmaf(xv[j], scv[j], shv[j]), 0.f));
        }
        const int kb = kt * 4 + q;
#pragma unroll
        for (int t = 0; t < 4; ++t)
#pragma unroll
            for (int n = 0; n < 8; ++n) {
                const bf16x8 wfrag =
                    *(const bf16x8*)(ws[t] + (size_t)kb * 1024 + (n * 16 + c16) * 8);
                acc[t][n] = __builtin_amdgcn_mfma_f32_16x16x32_bf16(wfrag, afrag, acc[t][n], 0, 0, 0);
            }
    }

    const float* const bs[4] = {b0, b1, b2, b3};
#pragma unroll
    for (int t = 0; t < 4; ++t) {
#pragma unroll
        for (int n = 0; n < 8; ++n) {
            const int col = n * 16 + q * 4;
            const float4 b4 = *(const float4*)(bs[t] + col);
            const float v[4] = {acc[t][n][0] + b4.x, acc[t][n][1] + b4.y,
                                acc[t][n][2] + b4.z, acc[t][n][3] + b4.w};
            if (t == 0) {
                *(float4*)(Ah + (size_t)row * HH + col) = make_float4(v[0], v[1], v[2], v[3]);
            } else {
                bf16x4 o;
#pragma unroll
                for (int j = 0; j < 4; ++j) o[j] = f2bf(v[j]);
                short* dstp = (t == 1) ? Bh : ((t == 2) ? Dh : Eh);
                *(bf16x4*)(dstp + (size_t)row * HH + col) = o;
            }
        }
    }
}

// Fused readout: logits = relu(relu(bn(hnew)) @ w1 + b1) @ w2 + b2 — z in regs.
__global__ __launch_bounds__(256)
void readout_k(const float* __restrict__ hnew, const float* __restrict__ bnp,
               const short* __restrict__ Wp, const float* __restrict__ b1,
               const float* __restrict__ w2, const float* __restrict__ b2,
               float* __restrict__ out)
{
    const int lane = threadIdx.x & 63;
    const int wave = threadIdx.x >> 6;
    const int q = lane >> 4;
    const int c16 = lane & 15;
    const int row = blockIdx.x * 64 + wave * 16 + c16;

    f32x4 acc[8];
#pragma unroll
    for (int n = 0; n < 8; ++n) acc[n] = (f32x4){0.f, 0.f, 0.f, 0.f};

#pragma unroll
    for (int kt = 0; kt < 4; ++kt) {
        const int kbase = kt * 32 + q * 8;
        const float* p = hnew + (size_t)row * HH + kbase;
        const float4 x = *(const float4*)p;
        const float4 y = *(const float4*)(p + 4);
        const float4 s0 = *(const float4*)(bnp + kbase);
        const float4 s1 = *(const float4*)(bnp + kbase + 4);
        const float4 t0 = *(const float4*)(bnp + HH + kbase);
        const float4 t1 = *(const float4*)(bnp + HH + kbase + 4);
        const float xv[8] = {x.x, x.y, x.z, x.w, y.x, y.y, y.z, y.w};
        const float scv[8] = {s0.x, s0.y, s0.z, s0.w, s1.x, s1.y, s1.z, s1.w};
        const float shv[8] = {t0.x, t0.y, t0.z, t0.w, t1.x, t1.y, t1.z, t1.w};
        bf16x8 afrag;
#pragma unroll
        for (int j = 0; j < 8; ++j)
            afrag[j] = f2bf(fmaxf(fmaf(xv[j], scv[j], shv[j]), 0.f));
        const int kb = kt * 4 + q;
#pragma unroll
        for (int n = 0; n < 8; ++n) {
            const bf16x8 wfrag =
                *(const bf16x8*)(Wp + (size_t)kb * 1024 + (n * 16 + c16) * 8);
            acc[n] = __builtin_amdgcn_mfma_f32_16x16x32_bf16(wfrag, afrag, acc[n], 0, 0, 0);
        }
    }

    float part[NCLS] = {};
#pragma unroll
    for (int n = 0; n < 8; ++n) {
        const int col = n * 16 + q * 4;
        const float4 b4 = *(const float4*)(b1 + col);
        const float bb[4] = {b4.x, b4.y, b4.z, b4.w};
#pragma unroll
        for (int j = 0; j < 4; ++j) {
            const float zv = fmaxf(acc[n][j] + bb[j], 0.f);
#pragma unroll
            for (int t = 0; t < NCLS; ++t)
                part[t] = fmaf(zv, w2[(col + j) * NCLS + t], part[t]);
        }
    }
#pragma unroll
    for (int t = 0; t < NCLS; ++t) {
        part[t] += __shfl_xor(part[t], 16, 64);
        part[t] += __shfl_xor(part[t], 32, 64);
    }
    if (q == 0) {
#pragma unroll
        for (int t = 0; t < NCLS; ++t)
            out[(size_t)row * NCLS + t] = part[t] + b2[t];
    }
}

// Pack all weight matrices to bf16 fragments: Wp[kb][col][8] = W[kb*8+j][col].
__global__ __launch_bounds__(256)
void prepack_k(const float* __restrict__ enc_nw, const float* __restrict__ lin_w,
               const float* __restrict__ mlp_w1, short* __restrict__ wp)
{
    const int t = blockIdx.x * 256 + threadIdx.x;
    if (t >= 260 * 128) return;
    const int kbg = t >> 7, col = t & 127;
    const int kb0[11]  = {0, 100, 116, 132, 148, 164, 180, 196, 212, 228, 244};
    const int psel[11] = {0, 1, 1, 1, 1, 1, 1, 1, 1, 1, 2};
    const int soff[11] = {0, 0 * 16384, 1 * 16384, 3 * 16384, 4 * 16384,
                          5 * 16384, 6 * 16384, 7 * 16384, 8 * 16384, 9 * 16384, 0};
    const int Ksrc[11] = {KIN, 128, 128, 128, 128, 128, 128, 128, 128, 128, 128};
    int e = 10;
    while (e > 0 && kbg < kb0[e]) --e;
    const float* base = (psel[e] == 0) ? enc_nw : ((psel[e] == 1) ? lin_w : mlp_w1);
    const int kbl = kbg - kb0[e];
    bf16x8 o;
#pragma unroll
    for (int j = 0; j < 8; ++j) {
        const int k = kbl * 8 + j;
        const float v = (k < Ksrc[e]) ? base[(size_t)soff[e] + (size_t)k * HH + col] : 0.f;
        o[j] = f2bf(v);
    }
    *(bf16x8*)(wp + (size_t)kbg * 1024 + col * 8) = o;
}

// Rank-2 collapse of layer-1 edge GEMM.
__global__ void gpre_k(const float* __restrict__ enc_ew, const float* __restrict__ enc_eb,
                       const float* __restrict__ Wc, const float* __restrict__ bc,
                       float* __restrict__ G)
{
    const int c = threadIdx.x;
    float a0 = 0.f, a1 = 0.f, ab = 0.f;
    for (int k = 0; k < HH; ++k) {
        const float w = Wc[k * HH + c];
        a0 = fmaf(enc_ew[k], w, a0);
        a1 = fmaf(enc_ew[HH + k], w, a1);
        ab = fmaf(enc_eb[k], w, ab);
    }
    G[c] = a0; G[HH + c] = a1; G[2 * HH + c] = ab + bc[c];
}

// Layer-1 edge pass in dst-sorted space + e-BN stat partials.
__global__ __launch_bounds__(256)
void edge1_k(const float* __restrict__ ef, const int* __restrict__ eidx,
             const int* __restrict__ src_s, const int* __restrict__ dst_s,
             const float* __restrict__ G,
             const short* __restrict__ Dh, const short* __restrict__ Eh,
             short* __restrict__ enew, float* __restrict__ pbuf)
{
    const int tid = threadIdx.x;
    const int er = tid >> 4, cg = tid & 15;
    const int col = cg * 8;
    const float4 g00 = *(const float4*)(G + col);
    const float4 g01 = *(const float4*)(G + col + 4);
    const float4 g10 = *(const float4*)(G + HH + col);
    const float4 g11 = *(const float4*)(G + HH + col + 4);
    const float4 gb0 = *(const float4*)(G + 2 * HH + col);
    const float4 gb1 = *(const float4*)(G + 2 * HH + col + 4);
    const float G0v[8] = {g00.x, g00.y, g00.z, g00.w, g01.x, g01.y, g01.z, g01.w};
    const float G1v[8] = {g10.x, g10.y, g10.z, g10.w, g11.x, g11.y, g11.z, g11.w};
    const float GBv[8] = {gb0.x, gb0.y, gb0.z, gb0.w, gb1.x, gb1.y, gb1.z, gb1.w};
    float sa[8] = {}, qa[8] = {};
    for (int it = 0; it < 16; ++it) {
        const int i = blockIdx.x * 256 + it * 16 + er;
        const int e = eidx[i];
        const float f0 = ef[(size_t)e * 2];
        const float f1 = ef[(size_t)e * 2 + 1];
        const int s = src_s[i], d = dst_s[i];
        const bf16x8 dh = *(const bf16x8*)(Dh + (size_t)s * HH + col);
        const bf16x8 eh = *(const bf16x8*)(Eh + (size_t)d * HH + col);
        bf16x8 o;
#pragma unroll
        for (int j = 0; j < 8; ++j) {
            const float v = fmaf(f0, G0v[j], fmaf(f1, G1v[j], GBv[j]))
                            + bf2f(dh[j]) + bf2f(eh[j]);
            sa[j] += v; qa[j] += v * v;
            o[j] = f2bf(v);
        }
        *(bf16x8*)(enew + (size_t)i * HH + col) = o;
    }
    __shared__ float sred[16][136];
    const int slot = (blockIdx.x & 63) * 256;
#pragma unroll
    for (int j = 0; j < 8; ++j) sred[er][col + j] = sa[j];
    __syncthreads();
    for (int s2 = 8; s2 > 0; s2 >>= 1) {
        if (er < s2)
#pragma unroll
            for (int j = 0; j < 8; ++j) sred[er][col + j] += sred[er + s2][col + j];
        __syncthreads();
    }
    if (er == 0)
#pragma unroll
        for (int j = 0; j < 8; ++j) atomicAdd(pbuf + slot + col + j, sred[0][col + j]);
    __syncthreads();
#pragma unroll
    for (int j = 0; j < 8; ++j) sred[er][col + j] = qa[j];
    __syncthreads();
    for (int s2 = 8; s2 > 0; s2 >>= 1) {
        if (er < s2)
#pragma unroll
            for (int j = 0; j < 8; ++j) sred[er][col + j] += sred[er + s2][col + j];
        __syncthreads();
    }
    if (er == 0)
#pragma unroll
        for (int j = 0; j < 8; ++j) atomicAdd(pbuf + slot + 128 + col + j, sred[0][col + j]);
}

// ---- CSR build ----
__global__ __launch_bounds__(256)
void hist_k(const int* __restrict__ dst, int* __restrict__ cnt)
{
    const int e = blockIdx.x * 256 + threadIdx.x;
    if (e < NE) atomicAdd(cnt + dst[e], 1);
}

__global__ __launch_bounds__(1024)
void scan_k(const int* __restrict__ cnt, int* __restrict__ rowptr, int* __restrict__ wr)
{
    __shared__ int s[1024];
    const int t = threadIdx.x;
    const int base = t * 40;
    int sum = 0;
    for (int i = 0; i < 40; ++i) {
        const int idx = base + i;
        if (idx < NN) sum += cnt[idx];
    }
    s[t] = sum;
    __syncthreads();
    for (int off = 1; off < 1024; off <<= 1) {
        const int v = (t >= off) ? s[t - off] : 0;
        __syncthreads();
        s[t] += v;
        __syncthreads();
    }
    int run = (t == 0) ? 0 : s[t - 1];
    for (int i = 0; i < 40; ++i) {
        const int idx = base + i;
        if (idx < NN) {
            rowptr[idx] = run;
            wr[idx] = run;
            run += cnt[idx];
        }
    }
    if (t == 1023) rowptr[NN] = s[1023];
}

__global__ __launch_bounds__(256)
void scatter_k2(const int* __restrict__ dst, const int* __restrict__ src,
                int* __restrict__ wr, int* __restrict__ eidx,
                int* __restrict__ src_s, int* __restrict__ dst_s)
{
    const int e = blockIdx.x * 256 + threadIdx.x;
    if (e < NE) {
        const int d = dst[e];
        const int p = atomicAdd(wr + d, 1);
        eidx[p] = e;
        src_s[p] = src[e];
        dst_s[p] = d;
    }
}

// Vectorized per-node CSR reduction. Wave = 8 nodes sequential; within wave:
// slot = lane>>4 (4 edge-slots), cg = lane&15 (8 cols each, bf16x8 loads).
// shfl_xor(16/32) reduces slots; slot-0 lanes finish hnew + BN stat partials.
__global__ __launch_bounds__(256)
void seg_reduce_v(const short* __restrict__ enew, const int* __restrict__ rowptr,
                  const int* __restrict__ src_s, const short* __restrict__ Bh,
                  const float* __restrict__ Ah, float* __restrict__ hnew,
                  float* __restrict__ pbuf)
{
    const int wv = threadIdx.x >> 6;
    const int lane = threadIdx.x & 63;
    const int slot = lane >> 4;
    const int cg = lane & 15;
    const int col = cg * 8;
    const int n0 = (blockIdx.x * 4 + wv) * 8;
    float sa[8] = {}, qa[8] = {};
    for (int nn = 0; nn < 8; ++nn) {
        const int n = n0 + nn;
        const int k0 = rowptr[n], k1 = rowptr[n + 1];
        float num[8] = {}, den[8] = {};
        for (int k = k0 + slot; k < k1; k += 4) {
            const bf16x8 ev = *(const bf16x8*)(enew + (size_t)k * HH + col);
            const int s = src_s[k];
            const bf16x8 bv = *(const bf16x8*)(Bh + (size_t)s * HH + col);
#pragma unroll
            for (int j = 0; j < 8; ++j) {
                const float sg = 1.f / (1.f + __expf(-bf2f(ev[j])));
                den[j] += sg;
                num[j] = fmaf(sg, bf2f(bv[j]), num[j]);
            }
        }
#pragma unroll
        for (int j = 0; j < 8; ++j) {
            num[j] += __shfl_xor(num[j], 16, 64);
            den[j] += __shfl_xor(den[j], 16, 64);
            num[j] += __shfl_xor(num[j], 32, 64);
            den[j] += __shfl_xor(den[j], 32, 64);
        }
        if (slot == 0) {
            const size_t idx = (size_t)n * HH + col;
            const float4 a0 = *(const float4*)(Ah + idx);
            const float4 a1 = *(const float4*)(Ah + idx + 4);
            const float av[8] = {a0.x, a0.y, a0.z, a0.w, a1.x, a1.y, a1.z, a1.w};
            float x[8];
#pragma unroll
            for (int j = 0; j < 8; ++j) {
                x[j] = av[j] + num[j] / (den[j] + 1e-6f);
                sa[j] += x[j]; qa[j] += x[j] * x[j];
            }
            *(float4*)(hnew + idx) = make_float4(x[0], x[1], x[2], x[3]);
            *(float4*)(hnew + idx + 4) = make_float4(x[4], x[5], x[6], x[7]);
        }
    }
    if (slot == 0) {
        const int sl = (blockIdx.x & 63) * 256;
#pragma unroll
        for (int j = 0; j < 8; ++j) {
            atomicAdd(pbuf + sl + col + j, sa[j]);
            atomicAdd(pbuf + sl + 128 + col + j, qa[j]);
        }
    }
}

// BN params from 64-slot partials.
__global__ void make_bnp2(const float* __restrict__ pbuf, const float* __restrict__ g,
                          const float* __restrict__ b, float cntInv,
                          float* __restrict__ out)
{
    const int c = threadIdx.x;
    float s = 0.f, q = 0.f;
    for (int i = 0; i < 64; ++i) {
        s += pbuf[i * 256 + c];
        q += pbuf[i * 256 + 128 + c];
    }
    const float m = s * cntInv;
    const float var = q * cntInv - m * m;
    const float rs = rsqrtf(var + 1e-5f);
    const float sc = g[c] * rs;
    out[c] = sc;
    out[128 + c] = b[c] - m * sc;
}

extern "C" void kernel_launch(void* const* d_in, const int* in_sizes, int n_in,
                              void* d_out, int out_size, void* d_ws, size_t ws_size,
                              hipStream_t stream)
{
    const float* node_feat = (const float*)d_in[0];
    const float* edge_feat = (const float*)d_in[1];
    const int*   src       = (const int*)d_in[2];
    const int*   dst       = (const int*)d_in[3];
    const float* enc_nw    = (const float*)d_in[4];
    const float* enc_nb    = (const float*)d_in[5];
    const float* enc_ew    = (const float*)d_in[6];
    const float* enc_eb    = (const float*)d_in[7];
    const float* lin_w     = (const float*)d_in[8];
    const float* lin_b     = (const float*)d_in[9];
    const float* bnh_g     = (const float*)d_in[10];
    const float* bnh_b     = (const float*)d_in[11];
    const float* bne_g     = (const float*)d_in[12];
    const float* bne_b     = (const float*)d_in[13];
    const float* mlp_w1    = (const float*)d_in[14];
    const float* mlp_b1    = (const float*)d_in[15];
    const float* mlp_w2    = (const float*)d_in[16];
    const float* mlp_b2    = (const float*)d_in[17];
    float* out = (float*)d_out;

    char* base = (char*)d_ws;
    size_t off = 0;
    auto alloc = [&](size_t bytes) -> void* {
        void* p = base + off;
        off = (off + bytes + 255) & ~(size_t)255;
        return p;
    };
    const size_t NH = (size_t)NN * HH;
    float* hnew  = (float*)alloc(NH * 4);
    float* Ah    = (float*)alloc(NH * 4);
    short* h0    = (short*)alloc(NH * 2);
    short* Bh    = (short*)alloc(NH * 2);
    short* Dh    = (short*)alloc(NH * 2);
    short* Eh    = (short*)alloc(NH * 2);
    short* enew  = (short*)alloc((size_t)NE * HH * 2);
    short* wpack = (short*)alloc((size_t)260 * 1024 * 2);
    float* G     = (float*)alloc(384 * 4);
    float* bnpe  = (float*)alloc(256 * 4);
    float* bnph  = (float*)alloc(256 * 4);
    float* pbe   = (float*)alloc(16384 * 4);
    float* pbh0  = (float*)alloc(16384 * 4);
    float* pbh1  = (float*)alloc(16384 * 4);
    int* cnt     = (int*)alloc(NN * 4);
    int* rowptr  = (int*)alloc((NN + 1) * 4);
    int* wr      = (int*)alloc(NN * 4);
    int* eidx    = (int*)alloc((size_t)NE * 4);
    int* src_s   = (int*)alloc((size_t)NE * 4);
    int* dst_s   = (int*)alloc((size_t)NE * 4);

    const dim3 blk(256);

    hipMemsetAsync(cnt, 0, NN * 4, stream);
    hipMemsetAsync(pbe, 0, 3 * 16384 * 4, stream);   // pbe,pbh0,pbh1 contiguous
    hist_k<<<2500, blk, 0, stream>>>(dst, cnt);
    scan_k<<<1, 1024, 0, stream>>>(cnt, rowptr, wr);
    scatter_k2<<<2500, blk, 0, stream>>>(dst, src, wr, eidx, src_s, dst_s);
    prepack_k<<<130, blk, 0, stream>>>(enc_nw, lin_w, mlp_w1, wpack);
    gpre_k<<<1, 128, 0, stream>>>(enc_ew, enc_eb, lin_w + 2 * 16384, lin_b + 2 * HH, G);

    // encoder: h0 = bf16(node_feat @ enc_nw + enc_nb)
    mfma_gemm<25, true><<<625, blk, 0, stream>>>(node_feat, wpack, enc_nb, h0, KIN);

    // ---- layer 0 ----
    {
        const float* Bv = lin_b;
        fused4_k<false><<<625, blk, 0, stream>>>(
            h0, nullptr, nullptr,
            wpack + (size_t)100 * 1024, wpack + (size_t)116 * 1024,
            wpack + (size_t)132 * 1024, wpack + (size_t)148 * 1024,
            Bv + 0 * HH, Bv + 1 * HH, Bv + 3 * HH, Bv + 4 * HH,
            Ah, Bh, Dh, Eh);
        edge1_k<<<2500, blk, 0, stream>>>(edge_feat, eidx, src_s, dst_s, G,
                                          Dh, Eh, enew, pbe);
        make_bnp2<<<1, 128, 0, stream>>>(pbe, bne_g, bne_b, 1.f / NE, bnpe);
        seg_reduce_v<<<1250, blk, 0, stream>>>(enew, rowptr, src_s, Bh, Ah, hnew, pbh0);
        make_bnp2<<<1, 128, 0, stream>>>(pbh0, bnh_g, bnh_b, 1.f / NN, bnph);
    }

    // ---- layer 1 ----
    {
        const float* Bv = lin_b + 5 * HH;
        fused4_k<true><<<625, blk, 0, stream>>>(
            nullptr, hnew, bnph,
            wpack + (size_t)164 * 1024, wpack + (size_t)180 * 1024,
            wpack + (size_t)212 * 1024, wpack + (size_t)228 * 1024,
            Bv + 0 * HH, Bv + 1 * HH, Bv + 3 * HH, Bv + 4 * HH,
            Ah, Bh, Dh, Eh);
        edge2_k<<<5000, blk, 0, stream>>>(enew, wpack + (size_t)196 * 1024,
                                          Bv + 2 * HH, bnpe, Dh, Eh, src_s, dst_s);
        seg_reduce_v<<<1250, blk, 0, stream>>>(enew, rowptr, src_s, Bh, Ah, hnew, pbh1);
        make_bnp2<<<1, 128, 0, stream>>>(pbh1, bnh_g + HH, bnh_b + HH, 1.f / NN, bnph);
    }

    // fused readout
    readout_k<<<625, blk, 0, stream>>>(hnew, bnph, wpack + (size_t)244 * 1024,
                                       mlp_b1, mlp_w2, mlp_b2, out);
}